// Round 8
// baseline (15515.286 us; speedup 1.0000x reference)
//
#include <hip/hip_runtime.h>
#include <math.h>

// OptNet IPM QP solve via Woodbury, Round 8: register-resident Cholesky in k_C.
//  M = Q + G^T D G;  M^{-1} = Qi - Qi G^T (Dinv + K)^{-1} G Qi,  K = G Qi G^T
// Rounds 5-7 plateaued because the 33KB LDS triangle caps residency at ~4
// waves/CU (LDS-capacity), exposing all LDS latency/barrier drains. Round 8:
// k_C holds the full 128x128 symmetric matrix in REGISTERS (thread t owns the
// 8x8 tile (t>>4, t&15); 64 VGPRs). Only the 16-wide panel is staged in LDS
// (8KB, XOR-swizzled 4-col chunks to avoid 16-way bank conflicts). Trailing
// updates accumulate in registers (no LDS RMW); tri-solve is register-push via
// LDS atomics. Same math as rounds 5-7.

#define B_TOT 2560
#define TB 32
#define NB (B_TOT/TB)

__device__ __forceinline__ int ROFF(int i){ return (i*(i+1))>>1; }
// padded-row packed lower triangle (k_prep only)
__device__ __forceinline__ int rowStart(int i){
  int a=i>>2, b=i&3;
  return ((a+1)*((a<<1)+b))<<2;
}
#define TRI_SZ 8448

__device__ __forceinline__ int rowOfIdx(int idx){
  int i = (int)((sqrtf(8.f*(float)idx+1.f)-1.f)*0.5f);
  while (((i+1)*(i+2)>>1) <= idx) ++i;
  while (((i*(i+1))>>1) > idx) --i;
  return i;
}

// ---- swizzled panel addressing: P[128 rows][16 cols], logical 4-col chunk q
// of row r stored at physical chunk (q + (r>>3)) & 3. Row pitch 16 floats. ----
__device__ __forceinline__ int paddr(int r, int q){
  return r*16 + 4*((q + (r>>3)) & 3);
}
__device__ __forceinline__ int paddrc(int r, int c){
  return r*16 + 4*(((c>>2) + (r>>3)) & 3) + (c&3);
}

// ---- Gauss-Jordan 16x16 diag block on swizzled panel P (wave0, lanes 0..15).
// On exit rows c0..c0+16 of P hold Linv (zeros above diag). ----
__device__ __forceinline__ void gj_panel(float* P, int c0, int lane){
  float rowA[16], rowW[16];
  const int r = lane;
  #pragma unroll
  for (int j=0;j<16;++j){ rowA[j]=0.f; rowW[j]=0.f; }
  if (r < 16){
    #pragma unroll
    for (int q=0;q<4;++q){
      float4 w = *(const float4*)&P[paddr(c0+r, q)];
      rowA[4*q+0]=w.x; rowA[4*q+1]=w.y; rowA[4*q+2]=w.z; rowA[4*q+3]=w.w;
    }
    #pragma unroll
    for (int j=0;j<16;++j) if (j>r) rowA[j]=0.f;
    #pragma unroll
    for (int j=0;j<16;++j) rowW[j] = (j==r)?1.f:0.f;
  }
  #pragma unroll
  for (int k=0;k<16;++k){
    float akk = __shfl(rowA[k], k, 64);
    akk = fmaxf(akk, 1e-12f);
    float linv = rsqrtf(akk);
    float lrk = rowA[k]*linv;                  // valid for r>=k
    if (r==k){
      #pragma unroll
      for (int c=0;c<16;++c) rowW[c] *= linv;  // final Linv row k
    }
    #pragma unroll
    for (int j=k+1;j<16;++j){
      float ljk = __shfl(lrk, j, 64);
      if (r>=j) rowA[j] = fmaf(-lrk, ljk, rowA[j]);
    }
    #pragma unroll
    for (int c=0;c<=k;++c){
      float wkc = __shfl(rowW[c], k, 64);
      if (r>k) rowW[c] = fmaf(-lrk, wkc, rowW[c]);
    }
  }
  if (r < 16){
    #pragma unroll
    for (int q=0;q<4;++q){
      float4 w; w.x=rowW[4*q+0]; w.y=rowW[4*q+1]; w.z=rowW[4*q+2]; w.w=rowW[4*q+3];
      *(float4*)&P[paddr(c0+r, q)] = w;
    }
  }
}

// ================= k_prep machinery (unchanged from round 7) =================
__device__ __forceinline__ void chol_diag_gj(float* tri, int c0, int lane){
  float rowA[16], rowW[16];
  const int r = lane;
  #pragma unroll
  for (int j=0;j<16;++j){ rowA[j]=0.f; rowW[j]=0.f; }
  if (r < 16){
    const float* src = &tri[rowStart(c0+r)+c0];
    #pragma unroll
    for (int q=0;q<4;++q){
      if (q <= (r>>2)){
        float4 w = *(const float4*)&src[4*q];
        rowA[4*q+0]=w.x; rowA[4*q+1]=w.y; rowA[4*q+2]=w.z; rowA[4*q+3]=w.w;
      }
    }
    #pragma unroll
    for (int j=0;j<16;++j) if (j>r) rowA[j]=0.f;
    #pragma unroll
    for (int j=0;j<16;++j) rowW[j] = (j==r)?1.f:0.f;
  }
  #pragma unroll
  for (int k=0;k<16;++k){
    float akk = __shfl(rowA[k], k, 64);
    akk = fmaxf(akk, 1e-12f);
    float linv = rsqrtf(akk);
    float lrk = rowA[k]*linv;
    if (r==k){
      #pragma unroll
      for (int c=0;c<16;++c) rowW[c] *= linv;
    }
    #pragma unroll
    for (int j=k+1;j<16;++j){
      float ljk = __shfl(lrk, j, 64);
      if (r>=j) rowA[j] = fmaf(-lrk, ljk, rowA[j]);
    }
    #pragma unroll
    for (int c=0;c<=k;++c){
      float wkc = __shfl(rowW[c], k, 64);
      if (r>k) rowW[c] = fmaf(-lrk, wkc, rowW[c]);
    }
  }
  if (r < 16){
    float* dst = &tri[rowStart(c0+r)+c0];
    #pragma unroll
    for (int q=0;q<4;++q){
      if (q <= (r>>2)){
        float4 w; w.x=rowW[4*q+0]; w.y=rowW[4*q+1]; w.z=rowW[4*q+2]; w.w=rowW[4*q+3];
        *(float4*)&dst[4*q] = w;
      }
    }
  }
}

__device__ void chol_factor(float* tri, int t, int lane, int wid){
  for (int kb=0; kb<8; ++kb){
    const int c0 = kb*16;
    if (wid==(kb&3)) chol_diag_gj(tri, c0, lane);
    __syncthreads();
    const int rem = 112 - c0;
    if (t < rem){
      const int r = c0+16+t;
      const int rb = rowStart(r)+c0;
      float a[16];
      #pragma unroll
      for (int q=0;q<4;++q){
        float4 w = *(const float4*)&tri[rb+4*q];
        a[4*q+0]=w.x; a[4*q+1]=w.y; a[4*q+2]=w.z; a[4*q+3]=w.w;
      }
      float x[16];
      #pragma unroll
      for (int c=0;c<16;++c){
        float acc=0.f;
        const int lb = rowStart(c0+c)+c0;
        #pragma unroll
        for (int q=0;q<=(c>>2);++q){
          float4 w = *(const float4*)&tri[lb+4*q];
          if (4*q+0<=c) acc = fmaf(w.x, a[4*q+0], acc);
          if (4*q+1<=c) acc = fmaf(w.y, a[4*q+1], acc);
          if (4*q+2<=c) acc = fmaf(w.z, a[4*q+2], acc);
          if (4*q+3<=c) acc = fmaf(w.w, a[4*q+3], acc);
        }
        x[c]=acc;
      }
      #pragma unroll
      for (int q=0;q<4;++q){
        float4 w; w.x=x[4*q+0]; w.y=x[4*q+1]; w.z=x[4*q+2]; w.w=x[4*q+3];
        *(float4*)&tri[rb+4*q] = w;
      }
    }
    __syncthreads();
    if (rem > 0){
      const int base = c0+16;
      const int R = rem>>2;
      const int ntile = (R*(R+1))>>1;
      for (int idx=t; idx<ntile; idx+=256){
        int I = rowOfIdx(idx);
        int J = idx - ROFF(I);
        int i0 = base + 4*I, j0 = base + 4*J;
        int ra0=rowStart(i0+0)+c0, ra1=rowStart(i0+1)+c0,
            ra2=rowStart(i0+2)+c0, ra3=rowStart(i0+3)+c0;
        int rb0=rowStart(j0+0)+c0, rb1=rowStart(j0+1)+c0,
            rb2=rowStart(j0+2)+c0, rb3=rowStart(j0+3)+c0;
        float acc[4][4];
        #pragma unroll
        for (int ii=0;ii<4;++ii)
          #pragma unroll
          for (int jj=0;jj<4;++jj) acc[ii][jj]=0.f;
        #pragma unroll
        for (int q=0;q<4;++q){
          float4 A0=*(const float4*)&tri[ra0+4*q];
          float4 A1=*(const float4*)&tri[ra1+4*q];
          float4 A2=*(const float4*)&tri[ra2+4*q];
          float4 A3=*(const float4*)&tri[ra3+4*q];
          float4 B0=*(const float4*)&tri[rb0+4*q];
          float4 B1=*(const float4*)&tri[rb1+4*q];
          float4 B2=*(const float4*)&tri[rb2+4*q];
          float4 B3=*(const float4*)&tri[rb3+4*q];
          #define DOT4(Ai,Bj) (fmaf(Ai.x,Bj.x,fmaf(Ai.y,Bj.y,fmaf(Ai.z,Bj.z,Ai.w*Bj.w))))
          acc[0][0]+=DOT4(A0,B0); acc[0][1]+=DOT4(A0,B1); acc[0][2]+=DOT4(A0,B2); acc[0][3]+=DOT4(A0,B3);
          acc[1][0]+=DOT4(A1,B0); acc[1][1]+=DOT4(A1,B1); acc[1][2]+=DOT4(A1,B2); acc[1][3]+=DOT4(A1,B3);
          acc[2][0]+=DOT4(A2,B0); acc[2][1]+=DOT4(A2,B1); acc[2][2]+=DOT4(A2,B2); acc[2][3]+=DOT4(A2,B3);
          acc[3][0]+=DOT4(A3,B0); acc[3][1]+=DOT4(A3,B1); acc[3][2]+=DOT4(A3,B2); acc[3][3]+=DOT4(A3,B3);
          #undef DOT4
        }
        #pragma unroll
        for (int ii=0;ii<4;++ii){
          #pragma unroll
          for (int jj=0;jj<4;++jj){
            int gi=i0+ii, gj=j0+jj;
            if (gi>=gj) tri[rowStart(gi)+gj] -= acc[ii][jj];
          }
        }
      }
    }
    __syncthreads();
  }
}

__global__ __launch_bounds__(256) void k_prep(const float* __restrict__ Q,
        const float* __restrict__ Gm, float* __restrict__ Qi, float* __restrict__ M1)
{
  __shared__ __align__(16) float tri[TRI_SZ];
  __shared__ float Xl[128*32];
  const int t = threadIdx.x;
  const int lane = t&63, wid = t>>6;
  for (int idx=t; idx<8256; idx+=256){
    int i = rowOfIdx(idx); int j = idx - ROFF(i);
    tri[rowStart(i)+j] = Q[i*128+j];
  }
  __syncthreads();
  chol_factor(tri, t, lane, wid);
  for (int cc=0; cc<8; ++cc){
    const int a0 = (cc&3)*32;
    const bool ident = (cc<4);
    for (int idx=t; idx<4096; idx+=256){
      int i=idx>>5, j=idx&31;
      Xl[idx] = ident ? ((i==(a0+j))?1.f:0.f) : Gm[(a0+j)*128+i];
    }
    __syncthreads();
    for (int kb=0;kb<8;++kb){
      const int c0=kb*16;
      if (t<32){
        float v[16], x[16];
        #pragma unroll
        for (int c=0;c<16;++c) v[c]=Xl[(c0+c)*32+t];
        #pragma unroll
        for (int c=0;c<16;++c){
          float acc=0.f;
          const int lb=rowStart(c0+c)+c0;
          #pragma unroll
          for (int cp=0;cp<16;++cp) if (cp<=c) acc=fmaf(tri[lb+cp], v[cp], acc);
          x[c]=acc;
        }
        #pragma unroll
        for (int c=0;c<16;++c) Xl[(c0+c)*32+t]=x[c];
      }
      __syncthreads();
      const int rem=112-c0;
      for (int rr=(t>>5); rr<rem; rr+=8){
        const int r=c0+16+rr, j=t&31;
        float acc=Xl[r*32+j];
        #pragma unroll
        for (int c=0;c<16;++c) acc = fmaf(-tri[rowStart(r)+c0+c], Xl[(c0+c)*32+j], acc);
        Xl[r*32+j]=acc;
      }
      __syncthreads();
    }
    for (int kb=7;kb>=0;--kb){
      const int c0=kb*16;
      if (t<32){
        float v[16], x[16];
        #pragma unroll
        for (int c=0;c<16;++c) v[c]=Xl[(c0+c)*32+t];
        #pragma unroll
        for (int c=0;c<16;++c){
          float acc=0.f;
          #pragma unroll
          for (int cp=0;cp<16;++cp) if (cp>=c) acc=fmaf(tri[rowStart(c0+cp)+c0+c], v[cp], acc);
          x[c]=acc;
        }
        #pragma unroll
        for (int c=0;c<16;++c) Xl[(c0+c)*32+t]=x[c];
      }
      __syncthreads();
      for (int rr=(t>>5); rr<c0; rr+=8){
        const int j=t&31;
        float acc=Xl[rr*32+j];
        #pragma unroll
        for (int c=0;c<16;++c) acc = fmaf(-tri[rowStart(c0+c)+rr], Xl[(c0+c)*32+j], acc);
        Xl[rr*32+j]=acc;
      }
      __syncthreads();
    }
    float* dst = ident ? Qi : M1;
    for (int idx=t; idx<4096; idx+=256){
      int i=idx>>5, j=idx&31;
      dst[i*128+a0+j] = Xl[idx];
    }
    __syncthreads();
  }
}

__global__ __launch_bounds__(256) void k_kmat(const float* __restrict__ Gm,
        const float* __restrict__ M1, float* __restrict__ K, float* __restrict__ Kd){
  const int idx = blockIdx.x*256 + threadIdx.x;
  const int a = idx>>7, bcol = idx&127;
  float a0=0.f,a1=0.f,a2=0.f,a3=0.f;
  #pragma unroll
  for (int j=0;j<128;j+=4){
    a0 = fmaf(Gm[a*128+j+0], M1[(j+0)*128+bcol], a0);
    a1 = fmaf(Gm[a*128+j+1], M1[(j+1)*128+bcol], a1);
    a2 = fmaf(Gm[a*128+j+2], M1[(j+2)*128+bcol], a2);
    a3 = fmaf(Gm[a*128+j+3], M1[(j+3)*128+bcol], a3);
  }
  float acc = (a0+a1)+(a2+a3);
  K[idx] = acc;
  if (a==bcol) Kd[a]=acc;
}

__global__ __launch_bounds__(256) void k_init(const float* __restrict__ p,
    float* __restrict__ Pt, float* __restrict__ S, float* __restrict__ LAM,
    float* __restrict__ GZ, float* __restrict__ QZ, float* __restrict__ Zst){
  int idx = blockIdx.x*256 + threadIdx.x;
  if (idx < 128*B_TOT){
    int i = idx/B_TOT, b = idx - i*B_TOT;
    Pt[idx] = p[b*128+i];
    S[idx]=1.f; LAM[idx]=1.f; GZ[idx]=0.f; QZ[idx]=0.f; Zst[idx]=0.f;
  }
}

// ---- k_B: stage1 + rhs = -(qz+p)+G^T wm ; tv = G Qi rhs (via M1^T) ----
__global__ __launch_bounds__(256) void k_B(const float* __restrict__ G,
    const float* __restrict__ M1, const float* __restrict__ Pt,
    const float* __restrict__ h,
    const float* __restrict__ S, const float* __restrict__ LAM,
    const float* __restrict__ GZ, const float* __restrict__ QZ,
    float* __restrict__ RHS, float* __restrict__ TV){
  __shared__ float wm_l[128*33];
  __shared__ float rhs_l[128*33];
  __shared__ float part_l[8*33];
  __shared__ float mu_l[TB];
  __shared__ float h_l[128];
  const int t=threadIdx.x, g=t>>5, bl=t&31;
  const int b = blockIdx.x*TB + bl;
  if (t<128) h_l[t]=h[t];
  __syncthreads();
  float sv[16], lv[16], rpv[16];
  float prod=0.f;
  #pragma unroll
  for (int q=0;q<16;++q){
    int i = g + 8*q;
    float s = S[i*B_TOT+b], l = LAM[i*B_TOT+b], gz = GZ[i*B_TOT+b];
    sv[q]=s; lv[q]=l; rpv[q]=gz+s-h_l[i];
    prod += s*l;
  }
  part_l[g*33+bl] = prod;
  __syncthreads();
  if (g==0){
    float m=0.f;
    #pragma unroll
    for (int q=0;q<8;++q) m += part_l[q*33+bl];
    mu_l[bl] = m*(1.f/128.f);
  }
  __syncthreads();
  const float mu = mu_l[bl];
  #pragma unroll
  for (int q=0;q<16;++q){
    int i=g+8*q;
    float rc = sv[q]*lv[q] - 0.1f*mu;
    wm_l[i*33+bl] = (rc - lv[q]*rpv[q])/sv[q] - lv[q];
  }
  __syncthreads();
  const int r0 = g*16;
  float acc[16];
  #pragma unroll
  for (int q=0;q<16;++q) acc[q] = -(QZ[(r0+q)*B_TOT+b] + Pt[(r0+q)*B_TOT+b]);
  #pragma unroll 2
  for (int j=0;j<128;++j){
    float wmv = wm_l[j*33+bl];
    const float4* gp = (const float4*)&G[j*128+r0];
    #pragma unroll
    for (int q4=0;q4<4;++q4){
      float4 gv = gp[q4];
      acc[4*q4+0]=fmaf(gv.x,wmv,acc[4*q4+0]);
      acc[4*q4+1]=fmaf(gv.y,wmv,acc[4*q4+1]);
      acc[4*q4+2]=fmaf(gv.z,wmv,acc[4*q4+2]);
      acc[4*q4+3]=fmaf(gv.w,wmv,acc[4*q4+3]);
    }
  }
  #pragma unroll
  for (int q=0;q<16;++q){
    rhs_l[(r0+q)*33+bl]=acc[q];
    RHS[(r0+q)*B_TOT+b]=acc[q];
  }
  __syncthreads();
  #pragma unroll
  for (int q=0;q<16;++q) acc[q]=0.f;
  #pragma unroll 2
  for (int j=0;j<128;++j){
    float rv = rhs_l[j*33+bl];
    const float4* mp = (const float4*)&M1[j*128+r0];
    #pragma unroll
    for (int q4=0;q4<4;++q4){
      float4 mv = mp[q4];
      acc[4*q4+0]=fmaf(mv.x,rv,acc[4*q4+0]);
      acc[4*q4+1]=fmaf(mv.y,rv,acc[4*q4+1]);
      acc[4*q4+2]=fmaf(mv.z,rv,acc[4*q4+2]);
      acc[4*q4+3]=fmaf(mv.w,rv,acc[4*q4+3]);
    }
  }
  #pragma unroll
  for (int q=0;q<16;++q) TV[(r0+q)*B_TOT+b]=acc[q];
}

// ---- k_C round 8: register-tile Cholesky, 256 threads per batch ----
__global__ __launch_bounds__(256) void k_C(const float* __restrict__ K,
    const float* __restrict__ Kd, const float* __restrict__ h,
    const float* __restrict__ TV,
    float* __restrict__ S, float* __restrict__ LAM, float* __restrict__ GZ,
    float* __restrict__ Y, float* __restrict__ ALPHA){
  __shared__ __align__(16) float P[128*16];     // swizzled panel, 8 KB
  __shared__ float scl_l[128];
  __shared__ float rhs[128];
  __shared__ float ybuf[32];                    // double-buffered 16
  __shared__ float red[4];
  const int t=threadIdx.x, b=blockIdx.x;
  const int lane=t&63, wid=t>>6;
  const int TI=t>>4, TJ=t&15;                   // 8x8 tile coords

  // --- stage 1: state, mu, scl, rhs ---
  float s_t=0.f,l_t=0.f,g_t=0.f,rp_t=0.f,rc_t=0.f,di_t=0.f,sc_t=0.f;
  float prod=0.f;
  if (t<128){
    s_t=S[t*B_TOT+b]; l_t=LAM[t*B_TOT+b]; g_t=GZ[t*B_TOT+b];
    rp_t=g_t+s_t-h[t];
    prod=s_t*l_t;
  }
  #pragma unroll
  for (int o=32;o>0;o>>=1) prod += __shfl_xor(prod,o,64);
  if (lane==0) red[wid]=prod;
  __syncthreads();
  const float mu=(red[0]+red[1]+red[2]+red[3])*(1.f/128.f);
  if (t<128){
    rc_t=s_t*l_t-0.1f*mu;
    di_t=fminf(s_t/l_t,1e30f);
    sc_t=rsqrtf(Kd[t]+di_t);
    scl_l[t]=sc_t;
    rhs[t]=TV[t*B_TOT+b]*sc_t;
  }
  if (t<32) ybuf[t]=0.f;
  __syncthreads();

  // --- build register tile A = equilibrated K~ (unit diag), symmetric full ---
  float A[8][8];
  {
    float scj[8];
    #pragma unroll
    for (int j=0;j<8;++j) scj[j]=scl_l[8*TJ+j];
    #pragma unroll
    for (int i=0;i<8;++i){
      const int gi=8*TI+i;
      const float sri=scl_l[gi];
      const float4* kp=(const float4*)&K[gi*128+8*TJ];
      float4 k0=kp[0], k1=kp[1];
      A[i][0]=k0.x*sri*scj[0]; A[i][1]=k0.y*sri*scj[1];
      A[i][2]=k0.z*sri*scj[2]; A[i][3]=k0.w*sri*scj[3];
      A[i][4]=k1.x*sri*scj[4]; A[i][5]=k1.y*sri*scj[5];
      A[i][6]=k1.z*sri*scj[6]; A[i][7]=k1.w*sri*scj[7];
    }
    if (TI==TJ){
      #pragma unroll
      for (int i=0;i<8;++i) A[i][i]=1.f;
    }
  }

  // --- blocked factorization, BS=16, panel in LDS, tiles in registers ---
  for (int kb=0;kb<8;++kb){
    const int c0=16*kb;
    // 1. panel owners write current A cols into P (rows >= c0)
    if ((TJ>>1)==kb && TI>=2*kb){
      const int qo=(TJ&1)*2;                    // logical chunk base
      #pragma unroll
      for (int i=0;i<8;++i){
        const int r=8*TI+i;
        float4 w0,w1;
        w0.x=A[i][0]; w0.y=A[i][1]; w0.z=A[i][2]; w0.w=A[i][3];
        w1.x=A[i][4]; w1.y=A[i][5]; w1.z=A[i][6]; w1.w=A[i][7];
        *(float4*)&P[paddr(r,qo)]   = w0;
        *(float4*)&P[paddr(r,qo+1)] = w1;
      }
    }
    __syncthreads();
    // 2. GJ: diag block -> Linv (wave0)
    if (wid==0) gj_panel(P, c0, lane);
    __syncthreads();
    // 3. panel solve rows c0+16..127: X = A_panel * Linv^T
    const int rem=112-c0;
    if (t<rem){
      const int r=c0+16+t;
      float a[16];
      #pragma unroll
      for (int q=0;q<4;++q){
        float4 w=*(const float4*)&P[paddr(r,q)];
        a[4*q+0]=w.x; a[4*q+1]=w.y; a[4*q+2]=w.z; a[4*q+3]=w.w;
      }
      float x[16];
      #pragma unroll
      for (int c=0;c<16;++c){
        float acc=0.f;
        #pragma unroll
        for (int cp=0;cp<16;++cp)
          if (cp<=c) acc=fmaf(P[paddrc(c0+c,cp)], a[cp], acc);
        x[c]=acc;
      }
      #pragma unroll
      for (int q=0;q<4;++q){
        float4 w; w.x=x[4*q+0]; w.y=x[4*q+1]; w.z=x[4*q+2]; w.w=x[4*q+3];
        *(float4*)&P[paddr(r,q)]=w;
      }
    }
    __syncthreads();
    // 4. trailing: A -= P_i . P_j^T (register accumulate); readback L/Linv
    if (TI>=2*kb+2 && TJ>=2*kb+2){
      #pragma unroll
      for (int q=0;q<4;++q){
        float4 Pi[8], Pj[8];
        #pragma unroll
        for (int i=0;i<8;++i) Pi[i]=*(const float4*)&P[paddr(8*TI+i,q)];
        #pragma unroll
        for (int j=0;j<8;++j) Pj[j]=*(const float4*)&P[paddr(8*TJ+j,q)];
        #pragma unroll
        for (int i=0;i<8;++i){
          #pragma unroll
          for (int j=0;j<8;++j){
            A[i][j]=fmaf(-Pi[i].x,Pj[j].x,A[i][j]);
            A[i][j]=fmaf(-Pi[i].y,Pj[j].y,A[i][j]);
            A[i][j]=fmaf(-Pi[i].z,Pj[j].z,A[i][j]);
            A[i][j]=fmaf(-Pi[i].w,Pj[j].w,A[i][j]);
          }
        }
      }
    }
    if ((TJ>>1)==kb && TI>=2*kb){
      const int qo=(TJ&1)*2;
      #pragma unroll
      for (int i=0;i<8;++i){
        const int r=8*TI+i;
        float4 w0=*(const float4*)&P[paddr(r,qo)];
        float4 w1=*(const float4*)&P[paddr(r,qo+1)];
        A[i][0]=w0.x; A[i][1]=w0.y; A[i][2]=w0.z; A[i][3]=w0.w;
        A[i][4]=w1.x; A[i][5]=w1.y; A[i][6]=w1.z; A[i][7]=w1.w;
      }
    }
    __syncthreads();
  }

  // --- forward solve: L y = rhs (register-push) ---
  for (int kb=0;kb<8;++kb){
    const int c0=16*kb;
    float* cur=&ybuf[(kb&1)*16];
    float* nxt=&ybuf[((kb+1)&1)*16];
    if ((TI>>1)==kb && (TJ>>1)==kb){           // y_blk += Linv * r_blk
      const int a8=(TI&1)*8, b8=(TJ&1)*8;
      #pragma unroll
      for (int i=0;i<8;++i){
        float acc=0.f;
        #pragma unroll
        for (int j=0;j<8;++j) acc=fmaf(A[i][j], rhs[c0+b8+j], acc);
        atomicAdd(&cur[a8+i], acc);
      }
    }
    __syncthreads();
    if ((TJ>>1)==kb && TI>=2*kb+2){            // rhs[r] -= L[r,blk] . y_blk
      const int b8=(TJ&1)*8;
      float yv[8];
      #pragma unroll
      for (int j=0;j<8;++j) yv[j]=cur[b8+j];
      #pragma unroll
      for (int i=0;i<8;++i){
        float acc=0.f;
        #pragma unroll
        for (int j=0;j<8;++j) acc=fmaf(A[i][j],yv[j],acc);
        atomicAdd(&rhs[8*TI+i], -acc);
      }
    }
    if (t<16) rhs[c0+t]=cur[t];
    else if (t<32) nxt[t-16]=0.f;
    __syncthreads();
  }
  // --- backward solve: L^T x = y (register-push) ---
  for (int kb=7;kb>=0;--kb){
    const int c0=16*kb;
    float* cur=&ybuf[((kb+1)&1)*16];
    float* nxt=&ybuf[(kb&1)*16];
    if ((TI>>1)==kb && (TJ>>1)==kb){           // x_blk += Linv^T * r_blk
      const int a8=(TI&1)*8, b8=(TJ&1)*8;
      #pragma unroll
      for (int j=0;j<8;++j){
        float acc=0.f;
        #pragma unroll
        for (int i=0;i<8;++i) acc=fmaf(A[i][j], rhs[c0+a8+i], acc);
        atomicAdd(&cur[b8+j], acc);
      }
    }
    __syncthreads();
    if ((TI>>1)==kb && TJ<2*kb){               // rhs[c'] -= L[blk,c'] . x_blk
      const int a8=(TI&1)*8;
      float xv[8];
      #pragma unroll
      for (int i=0;i<8;++i) xv[i]=cur[a8+i];
      #pragma unroll
      for (int j=0;j<8;++j){
        float acc=0.f;
        #pragma unroll
        for (int i=0;i<8;++i) acc=fmaf(A[i][j],xv[i],acc);
        atomicAdd(&rhs[8*TJ+j], -acc);
      }
    }
    if (t<16) rhs[c0+t]=cur[t];
    else if (t<32) nxt[t-16]=0.f;
    __syncthreads();
  }

  // --- epilogue: step computation, alpha, state update ---
  float y=0.f,gd=0.f,ds=0.f,dl=0.f;
  float ra=1e9f;
  if (t<128){
    y=rhs[t]*sc_t;
    gd=di_t*y;                                 // G dz = Dinv .* y (Woodbury)
    ds=-rp_t-gd;
    dl=(-rc_t-l_t*ds)/s_t;
    if (ds<0.f) ra=-s_t/ds;
    if (dl<0.f) ra=fminf(ra,-l_t/dl);
  }
  #pragma unroll
  for (int o=32;o>0;o>>=1) ra=fminf(ra,__shfl_xor(ra,o,64));
  if (lane==0) red[wid]=ra;
  __syncthreads();
  const float alpha=fminf(1.0f,
      0.99f*fminf(fminf(red[0],red[1]),fminf(red[2],red[3])));
  if (t<128){
    S[t*B_TOT+b]  =s_t+alpha*ds;
    LAM[t*B_TOT+b]=l_t+alpha*dl;
    GZ[t*B_TOT+b] =g_t+alpha*gd;
    Y[t*B_TOT+b]  =y;
  }
  if (t==0) ALPHA[b]=alpha;
}

// ---- k_D: v = rhs - G^T y ; dz = Qi v ; z += a dz ; qz += a v ----
__global__ __launch_bounds__(256) void k_D(const float* __restrict__ G,
    const float* __restrict__ Qi, const float* __restrict__ RHS,
    const float* __restrict__ Y, const float* __restrict__ ALPHA,
    float* __restrict__ Zst, float* __restrict__ QZ){
  __shared__ float y_l[128*33];
  __shared__ float v_l[128*33];
  const int t=threadIdx.x, g=t>>5, bl=t&31;
  const int b = blockIdx.x*TB + bl;
  #pragma unroll
  for (int q=0;q<16;++q){
    int i=g+8*q;
    y_l[i*33+bl] = Y[i*B_TOT+b];
  }
  const float alpha = ALPHA[b];
  __syncthreads();
  const int r0=g*16;
  float acc[16];
  #pragma unroll
  for (int q=0;q<16;++q) acc[q]=RHS[(r0+q)*B_TOT+b];
  #pragma unroll 2
  for (int j=0;j<128;++j){
    float yv = y_l[j*33+bl];
    const float4* gp=(const float4*)&G[j*128+r0];
    #pragma unroll
    for (int q4=0;q4<4;++q4){
      float4 gv=gp[q4];
      acc[4*q4+0]=fmaf(-gv.x,yv,acc[4*q4+0]);
      acc[4*q4+1]=fmaf(-gv.y,yv,acc[4*q4+1]);
      acc[4*q4+2]=fmaf(-gv.z,yv,acc[4*q4+2]);
      acc[4*q4+3]=fmaf(-gv.w,yv,acc[4*q4+3]);
    }
  }
  #pragma unroll
  for (int q=0;q<16;++q){
    v_l[(r0+q)*33+bl]=acc[q];
    float* qp=&QZ[(r0+q)*B_TOT+b];
    *qp = *qp + alpha*acc[q];
  }
  __syncthreads();
  #pragma unroll
  for (int q=0;q<16;++q) acc[q]=0.f;
  #pragma unroll 2
  for (int j=0;j<128;++j){
    float vv = v_l[j*33+bl];
    const float4* qp4=(const float4*)&Qi[j*128+r0];
    #pragma unroll
    for (int q4=0;q4<4;++q4){
      float4 qv=qp4[q4];
      acc[4*q4+0]=fmaf(qv.x,vv,acc[4*q4+0]);
      acc[4*q4+1]=fmaf(qv.y,vv,acc[4*q4+1]);
      acc[4*q4+2]=fmaf(qv.z,vv,acc[4*q4+2]);
      acc[4*q4+3]=fmaf(qv.w,vv,acc[4*q4+3]);
    }
  }
  #pragma unroll
  for (int q=0;q<16;++q){
    float* zp=&Zst[(r0+q)*B_TOT+b];
    *zp = *zp + alpha*acc[q];
  }
}

// out = log_softmax(Z.reshape(10, 32768), axis=1), Z stored n-major [i][B]
__global__ __launch_bounds__(1024) void k_logsoftmax(const float* __restrict__ Zst,
                                                     float* __restrict__ out){
  __shared__ float red[16];
  __shared__ float sval[2];
  const int r = blockIdx.x, t = threadIdx.x;
  float m = -1e30f;
  for (int k=t;k<32768;k+=1024){
    float v = Zst[(k&127)*B_TOT + r*256 + (k>>7)];
    m = fmaxf(m, v);
  }
  #pragma unroll
  for (int o=32;o>0;o>>=1) m = fmaxf(m, __shfl_down(m,o,64));
  if ((t&63)==0) red[t>>6] = m;
  __syncthreads();
  if (t==0){ float mm=red[0]; for (int w=1;w<16;++w) mm=fmaxf(mm,red[w]); sval[0]=mm; }
  __syncthreads();
  const float mx = sval[0];
  float s=0.f;
  for (int k=t;k<32768;k+=1024){
    float v = Zst[(k&127)*B_TOT + r*256 + (k>>7)];
    s += expf(v-mx);
  }
  #pragma unroll
  for (int o=32;o>0;o>>=1) s += __shfl_down(s,o,64);
  if ((t&63)==0) red[t>>6]=s;
  __syncthreads();
  if (t==0){ float ss=0.f; for (int w=0;w<16;++w) ss+=red[w]; sval[1]=logf(ss); }
  __syncthreads();
  const float lse = sval[1];
  for (int k=t;k<32768;k+=1024){
    float v = Zst[(k&127)*B_TOT + r*256 + (k>>7)];
    out[(size_t)r*32768+k] = v-mx-lse;
  }
}

extern "C" void kernel_launch(void* const* d_in, const int* in_sizes, int n_in,
                              void* d_out, int out_size, void* d_ws, size_t ws_size,
                              hipStream_t stream){
  // inputs: 0=x (unused), 1=Q[128x128], 2=p[2560x128], 3=G[128x128], 4=h[128], 5=m
  const float* Q = (const float*)d_in[1];
  const float* p = (const float*)d_in[2];
  const float* G = (const float*)d_in[3];
  const float* h = (const float*)d_in[4];
  float* ws  = (float*)d_ws;
  const int NE = 128*B_TOT;
  float* Zst = ws;
  float* Qi  = Zst + NE;
  float* M1  = Qi + 16384;
  float* K   = M1 + 16384;
  float* Kd  = K + 16384;
  float* ALPHA = Kd + 128;
  float* Pt  = ALPHA + 2560;
  float* S   = Pt + NE;
  float* LAM = S + NE;
  float* GZ  = LAM + NE;
  float* QZ  = GZ + NE;
  float* RHS = QZ + NE;
  float* TV  = RHS + NE;
  float* Y   = TV + NE;
  float* out = (float*)d_out;

  hipLaunchKernelGGL(k_prep, dim3(1), dim3(256), 0, stream, Q, G, Qi, M1);
  hipLaunchKernelGGL(k_kmat, dim3(64), dim3(256), 0, stream, G, M1, K, Kd);
  hipLaunchKernelGGL(k_init, dim3((NE+255)/256), dim3(256), 0, stream,
                     p, Pt, S, LAM, GZ, QZ, Zst);
  for (int it=0; it<20; ++it){
    hipLaunchKernelGGL(k_B, dim3(NB), dim3(256), 0, stream,
                       G, M1, Pt, h, S, LAM, GZ, QZ, RHS, TV);
    hipLaunchKernelGGL(k_C, dim3(B_TOT), dim3(256), 0, stream,
                       K, Kd, h, TV, S, LAM, GZ, Y, ALPHA);
    hipLaunchKernelGGL(k_D, dim3(NB), dim3(256), 0, stream,
                       G, Qi, RHS, Y, ALPHA, Zst, QZ);
  }
  hipLaunchKernelGGL(k_logsoftmax, dim3(10), dim3(1024), 0, stream, Zst, out);
}

// Round 9
// 14283.214 us; speedup vs baseline: 1.0863x; 1.0863x over previous
//
#include <hip/hip_runtime.h>
#include <math.h>

// OptNet IPM QP solve via Woodbury, Round 9: batch-inner vectorized Cholesky.
//  M = Q + G^T D G;  M^{-1} = Qi - Qi G^T (Dinv + K)^{-1} G Qi,  K = G Qi G^T
// Rounds 5-8: one block per batch pins residency at 4-8 waves/CU (33KB LDS
// triangle or register tiles) -> all LDS/barrier latency exposed, k_C ~350us.
// Round 9: triangle in GLOBAL memory TRI[8256 entries][2560 batches] (84.5MB,
// L3-resident). k_Cfac: 160 blocks x 512 threads, 16 batches per block;
// thread (rw,bl) works on batch lane bl -> every bulk phase is elementwise
// across batches: coalesced 64B loads, zero divergence, no serial chains.
// GJ diag runs 4 batches/wave via in-wave shuffles. k_B/k_D as round 7.

#define B_TOT 2560
#define TB 32
#define NB (B_TOT/TB)
#define BT 16
#define NBC (B_TOT/BT)        // 160 blocks for k_Cfac

__device__ __forceinline__ int ROFF(int i){ return (i*(i+1))>>1; }
// padded-row packed lower triangle (k_prep only)
__device__ __forceinline__ int rowStart(int i){
  int a=i>>2, b=i&3;
  return ((a+1)*((a<<1)+b))<<2;
}
#define TRI_SZ 8448

__device__ __forceinline__ int rowOfIdx(int idx){
  int i = (int)((sqrtf(8.f*(float)idx+1.f)-1.f)*0.5f);
  while (((i+1)*(i+2)>>1) <= idx) ++i;
  while (((i*(i+1))>>1) > idx) --i;
  return i;
}

// ================= k_prep machinery (unchanged, 256-thread LDS version) =====
__device__ __forceinline__ void chol_diag_gj(float* tri, int c0, int lane){
  float rowA[16], rowW[16];
  const int r = lane;
  #pragma unroll
  for (int j=0;j<16;++j){ rowA[j]=0.f; rowW[j]=0.f; }
  if (r < 16){
    const float* src = &tri[rowStart(c0+r)+c0];
    #pragma unroll
    for (int q=0;q<4;++q){
      if (q <= (r>>2)){
        float4 w = *(const float4*)&src[4*q];
        rowA[4*q+0]=w.x; rowA[4*q+1]=w.y; rowA[4*q+2]=w.z; rowA[4*q+3]=w.w;
      }
    }
    #pragma unroll
    for (int j=0;j<16;++j) if (j>r) rowA[j]=0.f;
    #pragma unroll
    for (int j=0;j<16;++j) rowW[j] = (j==r)?1.f:0.f;
  }
  #pragma unroll
  for (int k=0;k<16;++k){
    float akk = __shfl(rowA[k], k, 64);
    akk = fmaxf(akk, 1e-12f);
    float linv = rsqrtf(akk);
    float lrk = rowA[k]*linv;
    if (r==k){
      #pragma unroll
      for (int c=0;c<16;++c) rowW[c] *= linv;
    }
    #pragma unroll
    for (int j=k+1;j<16;++j){
      float ljk = __shfl(lrk, j, 64);
      if (r>=j) rowA[j] = fmaf(-lrk, ljk, rowA[j]);
    }
    #pragma unroll
    for (int c=0;c<=k;++c){
      float wkc = __shfl(rowW[c], k, 64);
      if (r>k) rowW[c] = fmaf(-lrk, wkc, rowW[c]);
    }
  }
  if (r < 16){
    float* dst = &tri[rowStart(c0+r)+c0];
    #pragma unroll
    for (int q=0;q<4;++q){
      if (q <= (r>>2)){
        float4 w; w.x=rowW[4*q+0]; w.y=rowW[4*q+1]; w.z=rowW[4*q+2]; w.w=rowW[4*q+3];
        *(float4*)&dst[4*q] = w;
      }
    }
  }
}

__device__ void chol_factor(float* tri, int t, int lane, int wid){
  for (int kb=0; kb<8; ++kb){
    const int c0 = kb*16;
    if (wid==(kb&3)) chol_diag_gj(tri, c0, lane);
    __syncthreads();
    const int rem = 112 - c0;
    if (t < rem){
      const int r = c0+16+t;
      const int rb = rowStart(r)+c0;
      float a[16];
      #pragma unroll
      for (int q=0;q<4;++q){
        float4 w = *(const float4*)&tri[rb+4*q];
        a[4*q+0]=w.x; a[4*q+1]=w.y; a[4*q+2]=w.z; a[4*q+3]=w.w;
      }
      float x[16];
      #pragma unroll
      for (int c=0;c<16;++c){
        float acc=0.f;
        const int lb = rowStart(c0+c)+c0;
        #pragma unroll
        for (int q=0;q<=(c>>2);++q){
          float4 w = *(const float4*)&tri[lb+4*q];
          if (4*q+0<=c) acc = fmaf(w.x, a[4*q+0], acc);
          if (4*q+1<=c) acc = fmaf(w.y, a[4*q+1], acc);
          if (4*q+2<=c) acc = fmaf(w.z, a[4*q+2], acc);
          if (4*q+3<=c) acc = fmaf(w.w, a[4*q+3], acc);
        }
        x[c]=acc;
      }
      #pragma unroll
      for (int q=0;q<4;++q){
        float4 w; w.x=x[4*q+0]; w.y=x[4*q+1]; w.z=x[4*q+2]; w.w=x[4*q+3];
        *(float4*)&tri[rb+4*q] = w;
      }
    }
    __syncthreads();
    if (rem > 0){
      const int base = c0+16;
      const int R = rem>>2;
      const int ntile = (R*(R+1))>>1;
      for (int idx=t; idx<ntile; idx+=256){
        int I = rowOfIdx(idx);
        int J = idx - ROFF(I);
        int i0 = base + 4*I, j0 = base + 4*J;
        int ra0=rowStart(i0+0)+c0, ra1=rowStart(i0+1)+c0,
            ra2=rowStart(i0+2)+c0, ra3=rowStart(i0+3)+c0;
        int rb0=rowStart(j0+0)+c0, rb1=rowStart(j0+1)+c0,
            rb2=rowStart(j0+2)+c0, rb3=rowStart(j0+3)+c0;
        float acc[4][4];
        #pragma unroll
        for (int ii=0;ii<4;++ii)
          #pragma unroll
          for (int jj=0;jj<4;++jj) acc[ii][jj]=0.f;
        #pragma unroll
        for (int q=0;q<4;++q){
          float4 A0=*(const float4*)&tri[ra0+4*q];
          float4 A1=*(const float4*)&tri[ra1+4*q];
          float4 A2=*(const float4*)&tri[ra2+4*q];
          float4 A3=*(const float4*)&tri[ra3+4*q];
          float4 B0=*(const float4*)&tri[rb0+4*q];
          float4 B1=*(const float4*)&tri[rb1+4*q];
          float4 B2=*(const float4*)&tri[rb2+4*q];
          float4 B3=*(const float4*)&tri[rb3+4*q];
          #define DOT4(Ai,Bj) (fmaf(Ai.x,Bj.x,fmaf(Ai.y,Bj.y,fmaf(Ai.z,Bj.z,Ai.w*Bj.w))))
          acc[0][0]+=DOT4(A0,B0); acc[0][1]+=DOT4(A0,B1); acc[0][2]+=DOT4(A0,B2); acc[0][3]+=DOT4(A0,B3);
          acc[1][0]+=DOT4(A1,B0); acc[1][1]+=DOT4(A1,B1); acc[1][2]+=DOT4(A1,B2); acc[1][3]+=DOT4(A1,B3);
          acc[2][0]+=DOT4(A2,B0); acc[2][1]+=DOT4(A2,B1); acc[2][2]+=DOT4(A2,B2); acc[2][3]+=DOT4(A2,B3);
          acc[3][0]+=DOT4(A3,B0); acc[3][1]+=DOT4(A3,B1); acc[3][2]+=DOT4(A3,B2); acc[3][3]+=DOT4(A3,B3);
          #undef DOT4
        }
        #pragma unroll
        for (int ii=0;ii<4;++ii){
          #pragma unroll
          for (int jj=0;jj<4;++jj){
            int gi=i0+ii, gj=j0+jj;
            if (gi>=gj) tri[rowStart(gi)+gj] -= acc[ii][jj];
          }
        }
      }
    }
    __syncthreads();
  }
}

__global__ __launch_bounds__(256) void k_prep(const float* __restrict__ Q,
        const float* __restrict__ Gm, float* __restrict__ Qi, float* __restrict__ M1)
{
  __shared__ __align__(16) float tri[TRI_SZ];
  __shared__ float Xl[128*32];
  const int t = threadIdx.x;
  const int lane = t&63, wid = t>>6;
  for (int idx=t; idx<8256; idx+=256){
    int i = rowOfIdx(idx); int j = idx - ROFF(i);
    tri[rowStart(i)+j] = Q[i*128+j];
  }
  __syncthreads();
  chol_factor(tri, t, lane, wid);
  for (int cc=0; cc<8; ++cc){
    const int a0 = (cc&3)*32;
    const bool ident = (cc<4);
    for (int idx=t; idx<4096; idx+=256){
      int i=idx>>5, j=idx&31;
      Xl[idx] = ident ? ((i==(a0+j))?1.f:0.f) : Gm[(a0+j)*128+i];
    }
    __syncthreads();
    for (int kb=0;kb<8;++kb){
      const int c0=kb*16;
      if (t<32){
        float v[16], x[16];
        #pragma unroll
        for (int c=0;c<16;++c) v[c]=Xl[(c0+c)*32+t];
        #pragma unroll
        for (int c=0;c<16;++c){
          float acc=0.f;
          const int lb=rowStart(c0+c)+c0;
          #pragma unroll
          for (int cp=0;cp<16;++cp) if (cp<=c) acc=fmaf(tri[lb+cp], v[cp], acc);
          x[c]=acc;
        }
        #pragma unroll
        for (int c=0;c<16;++c) Xl[(c0+c)*32+t]=x[c];
      }
      __syncthreads();
      const int rem=112-c0;
      for (int rr=(t>>5); rr<rem; rr+=8){
        const int r=c0+16+rr, j=t&31;
        float acc=Xl[r*32+j];
        #pragma unroll
        for (int c=0;c<16;++c) acc = fmaf(-tri[rowStart(r)+c0+c], Xl[(c0+c)*32+j], acc);
        Xl[r*32+j]=acc;
      }
      __syncthreads();
    }
    for (int kb=7;kb>=0;--kb){
      const int c0=kb*16;
      if (t<32){
        float v[16], x[16];
        #pragma unroll
        for (int c=0;c<16;++c) v[c]=Xl[(c0+c)*32+t];
        #pragma unroll
        for (int c=0;c<16;++c){
          float acc=0.f;
          #pragma unroll
          for (int cp=0;cp<16;++cp) if (cp>=c) acc=fmaf(tri[rowStart(c0+cp)+c0+c], v[cp], acc);
          x[c]=acc;
        }
        #pragma unroll
        for (int c=0;c<16;++c) Xl[(c0+c)*32+t]=x[c];
      }
      __syncthreads();
      for (int rr=(t>>5); rr<c0; rr+=8){
        const int j=t&31;
        float acc=Xl[rr*32+j];
        #pragma unroll
        for (int c=0;c<16;++c) acc = fmaf(-tri[rowStart(c0+c)+rr], Xl[(c0+c)*32+j], acc);
        Xl[rr*32+j]=acc;
      }
      __syncthreads();
    }
    float* dst = ident ? Qi : M1;
    for (int idx=t; idx<4096; idx+=256){
      int i=idx>>5, j=idx&31;
      dst[i*128+a0+j] = Xl[idx];
    }
    __syncthreads();
  }
}

__global__ __launch_bounds__(256) void k_kmat(const float* __restrict__ Gm,
        const float* __restrict__ M1, float* __restrict__ K, float* __restrict__ Kd){
  const int idx = blockIdx.x*256 + threadIdx.x;
  const int a = idx>>7, bcol = idx&127;
  float a0=0.f,a1=0.f,a2=0.f,a3=0.f;
  #pragma unroll
  for (int j=0;j<128;j+=4){
    a0 = fmaf(Gm[a*128+j+0], M1[(j+0)*128+bcol], a0);
    a1 = fmaf(Gm[a*128+j+1], M1[(j+1)*128+bcol], a1);
    a2 = fmaf(Gm[a*128+j+2], M1[(j+2)*128+bcol], a2);
    a3 = fmaf(Gm[a*128+j+3], M1[(j+3)*128+bcol], a3);
  }
  float acc = (a0+a1)+(a2+a3);
  K[idx] = acc;
  if (a==bcol) Kd[a]=acc;
}

__global__ __launch_bounds__(256) void k_init(const float* __restrict__ p,
    float* __restrict__ Pt, float* __restrict__ S, float* __restrict__ LAM,
    float* __restrict__ GZ, float* __restrict__ QZ, float* __restrict__ Zst){
  int idx = blockIdx.x*256 + threadIdx.x;
  if (idx < 128*B_TOT){
    int i = idx/B_TOT, b = idx - i*B_TOT;
    Pt[idx] = p[b*128+i];
    S[idx]=1.f; LAM[idx]=1.f; GZ[idx]=0.f; QZ[idx]=0.f; Zst[idx]=0.f;
  }
}

// ---- k_B: stage1 + rhs = -(qz+p)+G^T wm ; tv = G Qi rhs (via M1^T) ----
__global__ __launch_bounds__(256) void k_B(const float* __restrict__ G,
    const float* __restrict__ M1, const float* __restrict__ Pt,
    const float* __restrict__ h,
    const float* __restrict__ S, const float* __restrict__ LAM,
    const float* __restrict__ GZ, const float* __restrict__ QZ,
    float* __restrict__ RHS, float* __restrict__ TV){
  __shared__ float wm_l[128*33];
  __shared__ float rhs_l[128*33];
  __shared__ float part_l[8*33];
  __shared__ float mu_l[TB];
  __shared__ float h_l[128];
  const int t=threadIdx.x, g=t>>5, bl=t&31;
  const int b = blockIdx.x*TB + bl;
  if (t<128) h_l[t]=h[t];
  __syncthreads();
  float sv[16], lv[16], rpv[16];
  float prod=0.f;
  #pragma unroll
  for (int q=0;q<16;++q){
    int i = g + 8*q;
    float s = S[i*B_TOT+b], l = LAM[i*B_TOT+b], gz = GZ[i*B_TOT+b];
    sv[q]=s; lv[q]=l; rpv[q]=gz+s-h_l[i];
    prod += s*l;
  }
  part_l[g*33+bl] = prod;
  __syncthreads();
  if (g==0){
    float m=0.f;
    #pragma unroll
    for (int q=0;q<8;++q) m += part_l[q*33+bl];
    mu_l[bl] = m*(1.f/128.f);
  }
  __syncthreads();
  const float mu = mu_l[bl];
  #pragma unroll
  for (int q=0;q<16;++q){
    int i=g+8*q;
    float rc = sv[q]*lv[q] - 0.1f*mu;
    wm_l[i*33+bl] = (rc - lv[q]*rpv[q])/sv[q] - lv[q];
  }
  __syncthreads();
  const int r0 = g*16;
  float acc[16];
  #pragma unroll
  for (int q=0;q<16;++q) acc[q] = -(QZ[(r0+q)*B_TOT+b] + Pt[(r0+q)*B_TOT+b]);
  #pragma unroll 2
  for (int j=0;j<128;++j){
    float wmv = wm_l[j*33+bl];
    const float4* gp = (const float4*)&G[j*128+r0];
    #pragma unroll
    for (int q4=0;q4<4;++q4){
      float4 gv = gp[q4];
      acc[4*q4+0]=fmaf(gv.x,wmv,acc[4*q4+0]);
      acc[4*q4+1]=fmaf(gv.y,wmv,acc[4*q4+1]);
      acc[4*q4+2]=fmaf(gv.z,wmv,acc[4*q4+2]);
      acc[4*q4+3]=fmaf(gv.w,wmv,acc[4*q4+3]);
    }
  }
  #pragma unroll
  for (int q=0;q<16;++q){
    rhs_l[(r0+q)*33+bl]=acc[q];
    RHS[(r0+q)*B_TOT+b]=acc[q];
  }
  __syncthreads();
  #pragma unroll
  for (int q=0;q<16;++q) acc[q]=0.f;
  #pragma unroll 2
  for (int j=0;j<128;++j){
    float rv = rhs_l[j*33+bl];
    const float4* mp = (const float4*)&M1[j*128+r0];
    #pragma unroll
    for (int q4=0;q4<4;++q4){
      float4 mv = mp[q4];
      acc[4*q4+0]=fmaf(mv.x,rv,acc[4*q4+0]);
      acc[4*q4+1]=fmaf(mv.y,rv,acc[4*q4+1]);
      acc[4*q4+2]=fmaf(mv.z,rv,acc[4*q4+2]);
      acc[4*q4+3]=fmaf(mv.w,rv,acc[4*q4+3]);
    }
  }
  #pragma unroll
  for (int q=0;q<16;++q) TV[(r0+q)*B_TOT+b]=acc[q];
}

// ---- k_Cfac: batch-inner vectorized build + Cholesky + solve + step ----
// TRI layout: TRI[e*B_TOT + b], e = packed lower-tri index ROFF(i)+j.
// 512 threads: bl = t&15 (batch lane), rw = t>>4 (0..31 row workers).
__global__ __launch_bounds__(512) void k_Cfac(
    const float* __restrict__ K, const float* __restrict__ Kd,
    const float* __restrict__ h, const float* __restrict__ TV,
    float* __restrict__ S, float* __restrict__ LAM, float* __restrict__ GZ,
    float* __restrict__ TRI, float* __restrict__ Y, float* __restrict__ ALPHA)
{
  __shared__ float scl[128*16];     // scl[i*16+bl]
  __shared__ float rhs[128*16];
  __shared__ float Dg[136*17];      // diag block / Linv, Dg[idx*17+bl]
  __shared__ float part[32*17];
  __shared__ float muv[16], alp[16];
  __shared__ unsigned char r16[136];
  const int t = threadIdx.x;
  const int bl = t & 15, rw = t >> 4;
  const int lane = t & 63, wid = t >> 6;
  const int b0 = blockIdx.x * BT;
  const int b = b0 + bl;

  if (t < 136) r16[t] = (unsigned char)rowOfIdx(t);

  // --- phase A: mu, scl, rhs ---
  float prod = 0.f;
  #pragma unroll
  for (int q=0;q<4;++q){
    int i = rw + 32*q;
    prod = fmaf(S[i*B_TOT+b], LAM[i*B_TOT+b], prod);
  }
  part[rw*17+bl] = prod;
  __syncthreads();
  if (t < 16){
    float m=0.f;
    #pragma unroll
    for (int r=0;r<32;++r) m += part[r*17+t];
    muv[t] = m*(1.f/128.f);
  }
  __syncthreads();
  #pragma unroll
  for (int q=0;q<4;++q){
    int i = rw + 32*q;
    float s = S[i*B_TOT+b], l = LAM[i*B_TOT+b];
    float di = fminf(s/l, 1e30f);
    float sc = rsqrtf(Kd[i]+di);
    scl[i*16+bl] = sc;
    rhs[i*16+bl] = TV[i*B_TOT+b]*sc;
  }
  __syncthreads();

  // --- build: TRI = equilibrated S(Dinv+K)S, unit diag ---
  for (int i=0;i<128;++i){
    const int base = ROFF(i);
    const float sci = scl[i*16+bl];
    for (int j=rw; j<=i; j+=32){
      float v = (j==i)? 1.f : K[i*128+j]*sci*scl[j*16+bl];
      TRI[(base+j)*B_TOT + b] = v;
    }
  }
  __syncthreads();

  // --- blocked right-looking Cholesky, BS=16 ---
  for (int kb=0;kb<8;++kb){
    const int c0 = 16*kb;
    const int rem = 112 - c0;
    // stage diag block -> Dg
    for (int u=t; u<2176; u+=512){
      int idx = u>>4, bt = u&15;
      int r = r16[idx], c = idx - ((r*(r+1))>>1);
      Dg[idx*17+bt] = TRI[(ROFF(c0+r)+c0+c)*B_TOT + b0+bt];
    }
    __syncthreads();
    // GJ: factor+invert 16x16; waves 0..3, 4 batches per wave (in-wave shfl)
    if (wid < 4){
      const int r = lane & 15, bat = wid*4 + (lane>>4);
      float rowA[16], rowW[16];
      #pragma unroll
      for (int j=0;j<16;++j){
        rowA[j] = (j<=r)? Dg[(((r*(r+1))>>1)+j)*17 + bat] : 0.f;
        rowW[j] = (j==r)? 1.f : 0.f;
      }
      #pragma unroll
      for (int k=0;k<16;++k){
        float akk = __shfl(rowA[k], (lane&48)|k, 64);
        akk = fmaxf(akk, 1e-12f);
        float linv = rsqrtf(akk);
        float lrk = rowA[k]*linv;
        if (r==k){
          #pragma unroll
          for (int c=0;c<16;++c) rowW[c] *= linv;
        }
        #pragma unroll
        for (int j=k+1;j<16;++j){
          float ljk = __shfl(lrk, (lane&48)|j, 64);
          if (r>=j) rowA[j] = fmaf(-lrk, ljk, rowA[j]);
        }
        #pragma unroll
        for (int c=0;c<=k;++c){
          float wkc = __shfl(rowW[c], (lane&48)|k, 64);
          if (r>k) rowW[c] = fmaf(-lrk, wkc, rowW[c]);
        }
      }
      #pragma unroll
      for (int c=0;c<16;++c)
        if (c<=r) Dg[(((r*(r+1))>>1)+c)*17 + bat] = rowW[c];
    }
    __syncthreads();
    // write Linv back to TRI diag slots (needed by solves later)
    for (int u=t; u<2176; u+=512){
      int idx = u>>4, bt = u&15;
      int r = r16[idx], c = idx - ((r*(r+1))>>1);
      TRI[(ROFF(c0+r)+c0+c)*B_TOT + b0+bt] = Dg[idx*17+bt];
    }
    // panel solve: X = A_panel * Linv^T (rows c0+16..127)
    for (int rr=rw; rr<rem; rr+=32){
      const int r = c0+16+rr;
      const int rb = ROFF(r)+c0;
      float a[16], x[16];
      #pragma unroll
      for (int c=0;c<16;++c) a[c] = TRI[(rb+c)*B_TOT + b];
      #pragma unroll
      for (int c=0;c<16;++c){
        float acc=0.f;
        const int lb = ((c*(c+1))>>1)*17;
        #pragma unroll
        for (int cp=0;cp<16;++cp)
          if (cp<=c) acc = fmaf(Dg[lb + cp*17 + bl], a[cp], acc);
        x[c]=acc;
      }
      #pragma unroll
      for (int c=0;c<16;++c) TRI[(rb+c)*B_TOT + b] = x[c];
    }
    __syncthreads();
    // trailing: A -= P P^T, 8x8 register tiles over 16-row block pairs
    if (rem > 0){
      const int base = c0+16;
      const int nBk = rem>>4;
      const int nunits = ((nBk*(nBk+1))>>1)*4;
      for (int u=rw; u<nunits; u+=32){
        const int pidx = u>>2, sub = u&3;
        int bI = rowOfIdx(pidx);
        int bJ = pidx - ((bI*(bI+1))>>1);
        const int si = sub>>1, sj = sub&1;
        if (bI==bJ && sj>si) continue;
        const int i0 = base + 16*bI + 8*si;
        const int j0 = base + 16*bJ + 8*sj;
        int eI[8], eJ[8];
        #pragma unroll
        for (int ii=0;ii<8;++ii) eI[ii] = (ROFF(i0+ii)+c0)*B_TOT + b;
        #pragma unroll
        for (int jj=0;jj<8;++jj) eJ[jj] = (ROFF(j0+jj)+c0)*B_TOT + b;
        float acc[8][8];
        #pragma unroll
        for (int ii=0;ii<8;++ii)
          #pragma unroll
          for (int jj=0;jj<8;++jj) acc[ii][jj]=0.f;
        #pragma unroll 4
        for (int k=0;k<16;++k){
          float LI[8], LJ[8];
          #pragma unroll
          for (int ii=0;ii<8;++ii) LI[ii] = TRI[eI[ii] + k*B_TOT];
          #pragma unroll
          for (int jj=0;jj<8;++jj) LJ[jj] = TRI[eJ[jj] + k*B_TOT];
          #pragma unroll
          for (int ii=0;ii<8;++ii)
            #pragma unroll
            for (int jj=0;jj<8;++jj)
              acc[ii][jj] = fmaf(LI[ii], LJ[jj], acc[ii][jj]);
        }
        const bool dsub = (bI==bJ && si==sj);
        #pragma unroll
        for (int ii=0;ii<8;++ii){
          const int rb2 = ROFF(i0+ii);
          #pragma unroll
          for (int jj=0;jj<8;++jj){
            if (dsub && jj>ii) continue;
            const int e = (rb2 + j0+jj)*B_TOT + b;
            TRI[e] -= acc[ii][jj];
          }
        }
      }
    }
    __syncthreads();
  }

  // --- forward solve: L y = rhs ---
  for (int kb=0;kb<8;++kb){
    const int c0=16*kb, rem=112-c0;
    for (int u=t; u<2176; u+=512){
      int idx=u>>4, bt=u&15;
      int r=r16[idx], c=idx-((r*(r+1))>>1);
      Dg[idx*17+bt] = TRI[(ROFF(c0+r)+c0+c)*B_TOT + b0+bt];
    }
    __syncthreads();
    float accd=0.f;
    if (t<256){
      const int c=t>>4, blx=t&15;
      #pragma unroll
      for (int cp=0;cp<16;++cp)
        if (cp<=c) accd = fmaf(Dg[(((c*(c+1))>>1)+cp)*17+blx],
                               rhs[(c0+cp)*16+blx], accd);
    }
    __syncthreads();
    if (t<256) rhs[(c0+(t>>4))*16+(t&15)] = accd;
    __syncthreads();
    for (int rr=rw; rr<rem; rr+=32){
      const int r=c0+16+rr;
      const int rb=ROFF(r)+c0;
      float a2 = rhs[r*16+bl];
      #pragma unroll
      for (int c=0;c<16;++c)
        a2 = fmaf(-TRI[(rb+c)*B_TOT+b], rhs[(c0+c)*16+bl], a2);
      rhs[r*16+bl] = a2;
    }
    __syncthreads();
  }
  // --- backward solve: L^T x = y ---
  for (int kb=7;kb>=0;--kb){
    const int c0=16*kb;
    for (int u=t; u<2176; u+=512){
      int idx=u>>4, bt=u&15;
      int r=r16[idx], c=idx-((r*(r+1))>>1);
      Dg[idx*17+bt] = TRI[(ROFF(c0+r)+c0+c)*B_TOT + b0+bt];
    }
    __syncthreads();
    float accd=0.f;
    if (t<256){
      const int c=t>>4, blx=t&15;
      #pragma unroll
      for (int cp=0;cp<16;++cp)
        if (cp>=c) accd = fmaf(Dg[(((cp*(cp+1))>>1)+c)*17+blx],
                               rhs[(c0+cp)*16+blx], accd);
    }
    __syncthreads();
    if (t<256) rhs[(c0+(t>>4))*16+(t&15)] = accd;
    __syncthreads();
    for (int r=rw; r<c0; r+=32){
      float a2 = rhs[r*16+bl];
      #pragma unroll
      for (int c=0;c<16;++c)
        a2 = fmaf(-TRI[(ROFF(c0+c)+r)*B_TOT+b], rhs[(c0+c)*16+bl], a2);
      rhs[r*16+bl] = a2;
    }
    __syncthreads();
  }

  // --- epilogue: step, alpha, state update ---
  float s4[4],l4[4],g4[4],ds4[4],dl4[4],gd4[4],y4[4];
  float ra = 1e9f;
  const float mu = muv[bl];
  #pragma unroll
  for (int q=0;q<4;++q){
    int i = rw+32*q;
    float s=S[i*B_TOT+b], l=LAM[i*B_TOT+b], g=GZ[i*B_TOT+b];
    float rp = g+s-h[i];
    float rc = s*l - 0.1f*mu;
    float di = fminf(s/l,1e30f);
    float y = rhs[i*16+bl]*scl[i*16+bl];
    float gd = di*y;                      // G dz = Dinv .* y (Woodbury identity)
    float ds = -rp-gd;
    float dl = (-rc-l*ds)/s;
    if (ds<0.f) ra = fminf(ra,-s/ds);
    if (dl<0.f) ra = fminf(ra,-l/dl);
    s4[q]=s;l4[q]=l;g4[q]=g;ds4[q]=ds;dl4[q]=dl;gd4[q]=gd;y4[q]=y;
  }
  part[rw*17+bl]=ra;
  __syncthreads();
  if (t<16){
    float m=1e9f;
    #pragma unroll
    for (int r=0;r<32;++r) m=fminf(m,part[r*17+t]);
    alp[t]=fminf(1.0f, 0.99f*m);
  }
  __syncthreads();
  const float alpha = alp[bl];
  #pragma unroll
  for (int q=0;q<4;++q){
    int i=rw+32*q;
    S[i*B_TOT+b]  = s4[q]+alpha*ds4[q];
    LAM[i*B_TOT+b]= l4[q]+alpha*dl4[q];
    GZ[i*B_TOT+b] = g4[q]+alpha*gd4[q];
    Y[i*B_TOT+b]  = y4[q];
  }
  if (t<16) ALPHA[b0+t]=alp[t];
}

// ---- k_D: v = rhs - G^T y ; dz = Qi v ; z += a dz ; qz += a v ----
__global__ __launch_bounds__(256) void k_D(const float* __restrict__ G,
    const float* __restrict__ Qi, const float* __restrict__ RHS,
    const float* __restrict__ Y, const float* __restrict__ ALPHA,
    float* __restrict__ Zst, float* __restrict__ QZ){
  __shared__ float y_l[128*33];
  __shared__ float v_l[128*33];
  const int t=threadIdx.x, g=t>>5, bl=t&31;
  const int b = blockIdx.x*TB + bl;
  #pragma unroll
  for (int q=0;q<16;++q){
    int i=g+8*q;
    y_l[i*33+bl] = Y[i*B_TOT+b];
  }
  const float alpha = ALPHA[b];
  __syncthreads();
  const int r0=g*16;
  float acc[16];
  #pragma unroll
  for (int q=0;q<16;++q) acc[q]=RHS[(r0+q)*B_TOT+b];
  #pragma unroll 2
  for (int j=0;j<128;++j){
    float yv = y_l[j*33+bl];
    const float4* gp=(const float4*)&G[j*128+r0];
    #pragma unroll
    for (int q4=0;q4<4;++q4){
      float4 gv=gp[q4];
      acc[4*q4+0]=fmaf(-gv.x,yv,acc[4*q4+0]);
      acc[4*q4+1]=fmaf(-gv.y,yv,acc[4*q4+1]);
      acc[4*q4+2]=fmaf(-gv.z,yv,acc[4*q4+2]);
      acc[4*q4+3]=fmaf(-gv.w,yv,acc[4*q4+3]);
    }
  }
  #pragma unroll
  for (int q=0;q<16;++q){
    v_l[(r0+q)*33+bl]=acc[q];
    float* qp=&QZ[(r0+q)*B_TOT+b];
    *qp = *qp + alpha*acc[q];
  }
  __syncthreads();
  #pragma unroll
  for (int q=0;q<16;++q) acc[q]=0.f;
  #pragma unroll 2
  for (int j=0;j<128;++j){
    float vv = v_l[j*33+bl];
    const float4* qp4=(const float4*)&Qi[j*128+r0];
    #pragma unroll
    for (int q4=0;q4<4;++q4){
      float4 qv=qp4[q4];
      acc[4*q4+0]=fmaf(qv.x,vv,acc[4*q4+0]);
      acc[4*q4+1]=fmaf(qv.y,vv,acc[4*q4+1]);
      acc[4*q4+2]=fmaf(qv.z,vv,acc[4*q4+2]);
      acc[4*q4+3]=fmaf(qv.w,vv,acc[4*q4+3]);
    }
  }
  #pragma unroll
  for (int q=0;q<16;++q){
    float* zp=&Zst[(r0+q)*B_TOT+b];
    *zp = *zp + alpha*acc[q];
  }
}

// out = log_softmax(Z.reshape(10, 32768), axis=1), Z stored n-major [i][B]
__global__ __launch_bounds__(1024) void k_logsoftmax(const float* __restrict__ Zst,
                                                     float* __restrict__ out){
  __shared__ float red[16];
  __shared__ float sval[2];
  const int r = blockIdx.x, t = threadIdx.x;
  float m = -1e30f;
  for (int k=t;k<32768;k+=1024){
    float v = Zst[(k&127)*B_TOT + r*256 + (k>>7)];
    m = fmaxf(m, v);
  }
  #pragma unroll
  for (int o=32;o>0;o>>=1) m = fmaxf(m, __shfl_down(m,o,64));
  if ((t&63)==0) red[t>>6] = m;
  __syncthreads();
  if (t==0){ float mm=red[0]; for (int w=1;w<16;++w) mm=fmaxf(mm,red[w]); sval[0]=mm; }
  __syncthreads();
  const float mx = sval[0];
  float s=0.f;
  for (int k=t;k<32768;k+=1024){
    float v = Zst[(k&127)*B_TOT + r*256 + (k>>7)];
    s += expf(v-mx);
  }
  #pragma unroll
  for (int o=32;o>0;o>>=1) s += __shfl_down(s,o,64);
  if ((t&63)==0) red[t>>6]=s;
  __syncthreads();
  if (t==0){ float ss=0.f; for (int w=0;w<16;++w) ss+=red[w]; sval[1]=logf(ss); }
  __syncthreads();
  const float lse = sval[1];
  for (int k=t;k<32768;k+=1024){
    float v = Zst[(k&127)*B_TOT + r*256 + (k>>7)];
    out[(size_t)r*32768+k] = v-mx-lse;
  }
}

extern "C" void kernel_launch(void* const* d_in, const int* in_sizes, int n_in,
                              void* d_out, int out_size, void* d_ws, size_t ws_size,
                              hipStream_t stream){
  // inputs: 0=x (unused), 1=Q[128x128], 2=p[2560x128], 3=G[128x128], 4=h[128], 5=m
  const float* Q = (const float*)d_in[1];
  const float* p = (const float*)d_in[2];
  const float* G = (const float*)d_in[3];
  const float* h = (const float*)d_in[4];
  float* ws  = (float*)d_ws;
  const int NE = 128*B_TOT;
  float* Zst = ws;                       // NE
  float* Qi  = Zst + NE;                 // 16384
  float* M1  = Qi + 16384;
  float* K   = M1 + 16384;
  float* Kd  = K + 16384;                // 128
  float* ALPHA = Kd + 128;               // 2560
  float* Pt  = ALPHA + 2560;             // NE
  float* S   = Pt + NE;
  float* LAM = S + NE;
  float* GZ  = LAM + NE;
  float* QZ  = GZ + NE;
  float* RHS = QZ + NE;
  float* TV  = RHS + NE;
  float* Y   = TV + NE;
  float* TRI = Y + NE;                   // 8256*2560 floats (84.5 MB)
  float* out = (float*)d_out;

  hipLaunchKernelGGL(k_prep, dim3(1), dim3(256), 0, stream, Q, G, Qi, M1);
  hipLaunchKernelGGL(k_kmat, dim3(64), dim3(256), 0, stream, G, M1, K, Kd);
  hipLaunchKernelGGL(k_init, dim3((NE+255)/256), dim3(256), 0, stream,
                     p, Pt, S, LAM, GZ, QZ, Zst);
  for (int it=0; it<20; ++it){
    hipLaunchKernelGGL(k_B, dim3(NB), dim3(256), 0, stream,
                       G, M1, Pt, h, S, LAM, GZ, QZ, RHS, TV);
    hipLaunchKernelGGL(k_Cfac, dim3(NBC), dim3(512), 0, stream,
                       K, Kd, h, TV, S, LAM, GZ, TRI, Y, ALPHA);
    hipLaunchKernelGGL(k_D, dim3(NB), dim3(256), 0, stream,
                       G, Qi, RHS, Y, ALPHA, Zst, QZ);
  }
  hipLaunchKernelGGL(k_logsoftmax, dim3(10), dim3(1024), 0, stream, Zst, out);
}

// Round 10
// 12120.479 us; speedup vs baseline: 1.2801x; 1.1784x over previous
//
#include <hip/hip_runtime.h>
#include <math.h>

// OptNet IPM QP solve via Woodbury, Round 10: pipelined-GJ k_C + fused k_DB.
//  M = Q + G^T D G;  M^{-1} = Qi - Qi G^T (Dinv + K)^{-1} G Qi,  K = G Qi G^T
// Base = round 7 (best, 8.74 ms). Changes:
//  - k_C: GJ(kb) on wave0 runs CONCURRENTLY with the deferred bulk ("REST") of
//    trailing(kb-1) on wave1(+wave0 tail); only the 16x16 next-diag block ("D")
//    is updated eagerly each phase. Trailing uses 8x8 register tiles with
//    float4 RMW (was 4x4 + scalar).
//  - k_DB: fused k_D(iter i) + k_B(iter i+1), one 80-block kernel.
//  - k_prep split: k_prepA (factor, 1 block) + k_prepB (8 parallel solve chunks).

#define B_TOT 2560
#define TB 32
#define NB (B_TOT/TB)

__device__ __forceinline__ int ROFF(int i){ return (i*(i+1))>>1; }
// padded-row packed lower triangle: row i starts at rowStart(i), 16B aligned
__device__ __forceinline__ int rowStart(int i){
  int a=i>>2, b=i&3;
  return ((a+1)*((a<<1)+b))<<2;
}
#define TRI_SZ 8448

__device__ __forceinline__ int rowOfIdx(int idx){
  int i = (int)((sqrtf(8.f*(float)idx+1.f)-1.f)*0.5f);
  while (((i+1)*(i+2)>>1) <= idx) ++i;
  while (((i*(i+1))>>1) > idx) --i;
  return i;
}

// ---- Gauss-Jordan 16x16 diag block: factor AND invert (lanes 0..15 of one wave)
// On exit diag slots hold Linv (lower). ----
__device__ __forceinline__ void chol_diag_gj(float* tri, int c0, int lane){
  float rowA[16], rowW[16];
  const int r = lane;
  #pragma unroll
  for (int j=0;j<16;++j){ rowA[j]=0.f; rowW[j]=0.f; }
  if (r < 16){
    const float* src = &tri[rowStart(c0+r)+c0];
    #pragma unroll
    for (int q=0;q<4;++q){
      if (q <= (r>>2)){
        float4 w = *(const float4*)&src[4*q];
        rowA[4*q+0]=w.x; rowA[4*q+1]=w.y; rowA[4*q+2]=w.z; rowA[4*q+3]=w.w;
      }
    }
    #pragma unroll
    for (int j=0;j<16;++j) if (j>r) rowA[j]=0.f;
    #pragma unroll
    for (int j=0;j<16;++j) rowW[j] = (j==r)?1.f:0.f;
  }
  #pragma unroll
  for (int k=0;k<16;++k){
    float akk = __shfl(rowA[k], k, 64);
    akk = fmaxf(akk, 1e-12f);
    float linv = rsqrtf(akk);
    float lrk = rowA[k]*linv;
    if (r==k){
      #pragma unroll
      for (int c=0;c<16;++c) rowW[c] *= linv;
    }
    #pragma unroll
    for (int j=k+1;j<16;++j){
      float ljk = __shfl(lrk, j, 64);
      if (r>=j) rowA[j] = fmaf(-lrk, ljk, rowA[j]);
    }
    #pragma unroll
    for (int c=0;c<=k;++c){
      float wkc = __shfl(rowW[c], k, 64);
      if (r>k) rowW[c] = fmaf(-lrk, wkc, rowW[c]);
    }
  }
  if (r < 16){
    float* dst = &tri[rowStart(c0+r)+c0];
    #pragma unroll
    for (int q=0;q<4;++q){
      if (q <= (r>>2)){
        float4 w; w.x=rowW[4*q+0]; w.y=rowW[4*q+1]; w.z=rowW[4*q+2]; w.w=rowW[4*q+3];
        *(float4*)&dst[4*q] = w;
      }
    }
  }
}

// ---- 8x8 trailing tile: tri[i0..i0+8][j0..j0+8] -= P_i . P_j^T (inner 16 @pc0)
__device__ __forceinline__ void trail_tile8(float* tri, int pc0, int i0, int j0,
                                            bool diag){
  float4 Pi[8][4], Pj[8][4];
  #pragma unroll
  for (int ii=0;ii<8;++ii){
    const float* rp = &tri[rowStart(i0+ii)+pc0];
    #pragma unroll
    for (int q=0;q<4;++q) Pi[ii][q] = *(const float4*)&rp[4*q];
  }
  #pragma unroll
  for (int jj=0;jj<8;++jj){
    const float* rp = &tri[rowStart(j0+jj)+pc0];
    #pragma unroll
    for (int q=0;q<4;++q) Pj[jj][q] = *(const float4*)&rp[4*q];
  }
  float acc[8][8];
  #pragma unroll
  for (int ii=0;ii<8;++ii)
    #pragma unroll
    for (int jj=0;jj<8;++jj) acc[ii][jj]=0.f;
  #pragma unroll
  for (int q=0;q<4;++q){
    #pragma unroll
    for (int ii=0;ii<8;++ii){
      #pragma unroll
      for (int jj=0;jj<8;++jj){
        acc[ii][jj] = fmaf(Pi[ii][q].x, Pj[jj][q].x, acc[ii][jj]);
        acc[ii][jj] = fmaf(Pi[ii][q].y, Pj[jj][q].y, acc[ii][jj]);
        acc[ii][jj] = fmaf(Pi[ii][q].z, Pj[jj][q].z, acc[ii][jj]);
        acc[ii][jj] = fmaf(Pi[ii][q].w, Pj[jj][q].w, acc[ii][jj]);
      }
    }
  }
  if (!diag){
    #pragma unroll
    for (int ii=0;ii<8;++ii){
      float4* p = (float4*)&tri[rowStart(i0+ii)+j0];
      float4 v0=p[0], v1=p[1];
      v0.x-=acc[ii][0]; v0.y-=acc[ii][1]; v0.z-=acc[ii][2]; v0.w-=acc[ii][3];
      v1.x-=acc[ii][4]; v1.y-=acc[ii][5]; v1.z-=acc[ii][6]; v1.w-=acc[ii][7];
      p[0]=v0; p[1]=v1;
    }
  } else {
    // row i0+ii padded length covers chunks 0..(ii>>2); pad entries harmless
    #pragma unroll
    for (int ii=0;ii<8;++ii){
      float4* p = (float4*)&tri[rowStart(i0+ii)+j0];
      const int nq = (ii>>2)+1;
      #pragma unroll
      for (int q=0;q<2;++q){
        if (q<nq){
          float4 v=p[q];
          v.x-=acc[ii][4*q+0]; v.y-=acc[ii][4*q+1];
          v.z-=acc[ii][4*q+2]; v.w-=acc[ii][4*q+3];
          p[q]=v;
        }
      }
    }
  }
}

// ---- 4x4 trailing tile (for the eager next-diag "D" update) ----
__device__ __forceinline__ void trail_tile4(float* tri, int pc0, int i0, int j0){
  float4 Pi[4][4], Pj[4][4];
  #pragma unroll
  for (int ii=0;ii<4;++ii){
    const float* rp = &tri[rowStart(i0+ii)+pc0];
    #pragma unroll
    for (int q=0;q<4;++q) Pi[ii][q] = *(const float4*)&rp[4*q];
  }
  #pragma unroll
  for (int jj=0;jj<4;++jj){
    const float* rp = &tri[rowStart(j0+jj)+pc0];
    #pragma unroll
    for (int q=0;q<4;++q) Pj[jj][q] = *(const float4*)&rp[4*q];
  }
  float acc[4][4];
  #pragma unroll
  for (int ii=0;ii<4;++ii)
    #pragma unroll
    for (int jj=0;jj<4;++jj) acc[ii][jj]=0.f;
  #pragma unroll
  for (int q=0;q<4;++q){
    #pragma unroll
    for (int ii=0;ii<4;++ii){
      #pragma unroll
      for (int jj=0;jj<4;++jj){
        acc[ii][jj] = fmaf(Pi[ii][q].x, Pj[jj][q].x, acc[ii][jj]);
        acc[ii][jj] = fmaf(Pi[ii][q].y, Pj[jj][q].y, acc[ii][jj]);
        acc[ii][jj] = fmaf(Pi[ii][q].z, Pj[jj][q].z, acc[ii][jj]);
        acc[ii][jj] = fmaf(Pi[ii][q].w, Pj[jj][q].w, acc[ii][jj]);
      }
    }
  }
  #pragma unroll
  for (int ii=0;ii<4;++ii){
    float4* p = (float4*)&tri[rowStart(i0+ii)+j0];  // j0<=i0, 4-aligned: safe
    float4 v=p[0];
    v.x-=acc[ii][0]; v.y-=acc[ii][1]; v.z-=acc[ii][2]; v.w-=acc[ii][3];
    p[0]=v;
  }
}

// ---- panel solve row: X = A * Linv^T (one row, b128 masked) ----
__device__ __forceinline__ void panel_row(float* tri, int c0, int r){
  const int rb = rowStart(r)+c0;
  float a[16];
  #pragma unroll
  for (int q=0;q<4;++q){
    float4 w = *(const float4*)&tri[rb+4*q];
    a[4*q+0]=w.x; a[4*q+1]=w.y; a[4*q+2]=w.z; a[4*q+3]=w.w;
  }
  float x[16];
  #pragma unroll
  for (int c=0;c<16;++c){
    float acc=0.f;
    const int lb = rowStart(c0+c)+c0;
    #pragma unroll
    for (int q=0;q<=(c>>2);++q){
      float4 w = *(const float4*)&tri[lb+4*q];
      if (4*q+0<=c) acc = fmaf(w.x, a[4*q+0], acc);
      if (4*q+1<=c) acc = fmaf(w.y, a[4*q+1], acc);
      if (4*q+2<=c) acc = fmaf(w.z, a[4*q+2], acc);
      if (4*q+3<=c) acc = fmaf(w.w, a[4*q+3], acc);
    }
    x[c]=acc;
  }
  #pragma unroll
  for (int q=0;q<4;++q){
    float4 w; w.x=x[4*q+0]; w.y=x[4*q+1]; w.z=x[4*q+2]; w.w=x[4*q+3];
    *(float4*)&tri[rb+4*q] = w;
  }
}

// ---- 256-thread blocked Cholesky (k_prepA only, round-7 version) ----
__device__ void chol_factor(float* tri, int t, int lane, int wid){
  for (int kb=0; kb<8; ++kb){
    const int c0 = kb*16;
    if (wid==(kb&3)) chol_diag_gj(tri, c0, lane);
    __syncthreads();
    const int rem = 112 - c0;
    if (t < rem) panel_row(tri, c0, c0+16+t);
    __syncthreads();
    if (rem > 0){
      const int base = c0+16;
      const int T = rem>>3;
      const int ntile = (T*(T+1))>>1;
      for (int idx=t; idx<ntile; idx+=256){
        int I = rowOfIdx(idx);
        int J = idx - ROFF(I);
        trail_tile8(tri, c0, base+8*I, base+8*J, I==J);
      }
    }
    __syncthreads();
  }
}

// 128-thread forward/backward solve; diag slots hold Linv; rhs in LDS (r7)
__device__ void tri_solve_w2(const float* tri, float* rhs, int t){
  for (int kb=0;kb<8;++kb){
    const int c0=kb*16;
    if (t<16){
      const int c=t;
      const float* lrow = &tri[rowStart(c0+c)+c0];
      float acc=0.f;
      #pragma unroll
      for (int cp=0;cp<16;++cp) if (cp<=c) acc = fmaf(lrow[cp], rhs[c0+cp], acc);
      rhs[c0+c] = acc;
    }
    __syncthreads();
    const int rem = 112-c0;
    if (t<rem){
      const int r = c0+16+t;
      const int rb = rowStart(r)+c0;
      float acc = rhs[r];
      #pragma unroll
      for (int q=0;q<4;++q){
        float4 w = *(const float4*)&tri[rb+4*q];
        acc = fmaf(-w.x, rhs[c0+4*q+0], acc);
        acc = fmaf(-w.y, rhs[c0+4*q+1], acc);
        acc = fmaf(-w.z, rhs[c0+4*q+2], acc);
        acc = fmaf(-w.w, rhs[c0+4*q+3], acc);
      }
      rhs[r] = acc;
    }
    __syncthreads();
  }
  for (int kb=7;kb>=0;--kb){
    const int c0=kb*16;
    if (t<16){
      const int c=t;
      float acc=0.f;
      #pragma unroll
      for (int cp=0;cp<16;++cp)
        if (cp>=c) acc = fmaf(tri[rowStart(c0+cp)+c0+c], rhs[c0+cp], acc);
      rhs[c0+c] = acc;
    }
    __syncthreads();
    if (t<c0){
      float acc = rhs[t];
      #pragma unroll
      for (int c=0;c<16;++c) acc = fmaf(-tri[rowStart(c0+c)+t], rhs[c0+c], acc);
      rhs[t]=acc;
    }
    __syncthreads();
  }
}

// ---- k_prepA: factor chol(Q), dump triangle to global ----
__global__ __launch_bounds__(256) void k_prepA(const float* __restrict__ Q,
                                               float* __restrict__ TRIQ){
  __shared__ __align__(16) float tri[TRI_SZ];
  const int t = threadIdx.x;
  const int lane = t&63, wid = t>>6;
  for (int idx=t; idx<8256; idx+=256){
    int i = rowOfIdx(idx); int j = idx - ROFF(i);
    tri[rowStart(i)+j] = Q[i*128+j];
  }
  __syncthreads();
  chol_factor(tri, t, lane, wid);
  for (int idx=t; idx<TRI_SZ; idx+=256) TRIQ[idx]=tri[idx];
}

// ---- k_prepB: 8 blocks, each one 32-col solve chunk -> Qi or M1 ----
__global__ __launch_bounds__(256) void k_prepB(const float* __restrict__ TRIQ,
        const float* __restrict__ Gm, float* __restrict__ Qi, float* __restrict__ M1)
{
  __shared__ __align__(16) float tri[TRI_SZ];
  __shared__ float Xl[128*32];
  const int t = threadIdx.x, cc = blockIdx.x;
  const int a0 = (cc&3)*32;
  const bool ident = (cc<4);
  for (int idx=t; idx<TRI_SZ; idx+=256) tri[idx]=TRIQ[idx];
  for (int idx=t; idx<4096; idx+=256){
    int i=idx>>5, j=idx&31;
    Xl[idx] = ident ? ((i==(a0+j))?1.f:0.f) : Gm[(a0+j)*128+i];
  }
  __syncthreads();
  for (int kb=0;kb<8;++kb){                    // forward: X := L^{-1} X
    const int c0=kb*16;
    if (t<32){
      float v[16], x[16];
      #pragma unroll
      for (int c=0;c<16;++c) v[c]=Xl[(c0+c)*32+t];
      #pragma unroll
      for (int c=0;c<16;++c){
        float acc=0.f;
        const int lb=rowStart(c0+c)+c0;
        #pragma unroll
        for (int cp=0;cp<16;++cp) if (cp<=c) acc=fmaf(tri[lb+cp], v[cp], acc);
        x[c]=acc;
      }
      #pragma unroll
      for (int c=0;c<16;++c) Xl[(c0+c)*32+t]=x[c];
    }
    __syncthreads();
    const int rem=112-c0;
    for (int rr=(t>>5); rr<rem; rr+=8){
      const int r=c0+16+rr, j=t&31;
      float acc=Xl[r*32+j];
      #pragma unroll
      for (int c=0;c<16;++c) acc = fmaf(-tri[rowStart(r)+c0+c], Xl[(c0+c)*32+j], acc);
      Xl[r*32+j]=acc;
    }
    __syncthreads();
  }
  for (int kb=7;kb>=0;--kb){                   // backward: X := L^{-T} X
    const int c0=kb*16;
    if (t<32){
      float v[16], x[16];
      #pragma unroll
      for (int c=0;c<16;++c) v[c]=Xl[(c0+c)*32+t];
      #pragma unroll
      for (int c=0;c<16;++c){
        float acc=0.f;
        #pragma unroll
        for (int cp=0;cp<16;++cp) if (cp>=c) acc=fmaf(tri[rowStart(c0+cp)+c0+c], v[cp], acc);
        x[c]=acc;
      }
      #pragma unroll
      for (int c=0;c<16;++c) Xl[(c0+c)*32+t]=x[c];
    }
    __syncthreads();
    for (int rr=(t>>5); rr<c0; rr+=8){
      const int j=t&31;
      float acc=Xl[rr*32+j];
      #pragma unroll
      for (int c=0;c<16;++c) acc = fmaf(-tri[rowStart(c0+c)+rr], Xl[(c0+c)*32+j], acc);
      Xl[rr*32+j]=acc;
    }
    __syncthreads();
  }
  float* dst = ident ? Qi : M1;
  for (int idx=t; idx<4096; idx+=256){
    int i=idx>>5, j=idx&31;
    dst[i*128+a0+j] = Xl[idx];
  }
}

__global__ __launch_bounds__(256) void k_kmat(const float* __restrict__ Gm,
        const float* __restrict__ M1, float* __restrict__ K, float* __restrict__ Kd){
  const int idx = blockIdx.x*256 + threadIdx.x;
  const int a = idx>>7, bcol = idx&127;
  float a0=0.f,a1=0.f,a2=0.f,a3=0.f;
  #pragma unroll
  for (int j=0;j<128;j+=4){
    a0 = fmaf(Gm[a*128+j+0], M1[(j+0)*128+bcol], a0);
    a1 = fmaf(Gm[a*128+j+1], M1[(j+1)*128+bcol], a1);
    a2 = fmaf(Gm[a*128+j+2], M1[(j+2)*128+bcol], a2);
    a3 = fmaf(Gm[a*128+j+3], M1[(j+3)*128+bcol], a3);
  }
  float acc = (a0+a1)+(a2+a3);
  K[idx] = acc;
  if (a==bcol) Kd[a]=acc;
}

__global__ __launch_bounds__(256) void k_init(const float* __restrict__ p,
    float* __restrict__ Pt, float* __restrict__ S, float* __restrict__ LAM,
    float* __restrict__ GZ, float* __restrict__ QZ, float* __restrict__ Zst){
  int idx = blockIdx.x*256 + threadIdx.x;
  if (idx < 128*B_TOT){
    int i = idx/B_TOT, b = idx - i*B_TOT;
    Pt[idx] = p[b*128+i];
    S[idx]=1.f; LAM[idx]=1.f; GZ[idx]=0.f; QZ[idx]=0.f; Zst[idx]=0.f;
  }
}

// ---- k_B: stage1 + rhs = -(qz+p)+G^T wm ; tv = G Qi rhs (round 7) ----
__global__ __launch_bounds__(256) void k_B(const float* __restrict__ G,
    const float* __restrict__ M1, const float* __restrict__ Pt,
    const float* __restrict__ h,
    const float* __restrict__ S, const float* __restrict__ LAM,
    const float* __restrict__ GZ, const float* __restrict__ QZ,
    float* __restrict__ RHS, float* __restrict__ TV){
  __shared__ float wm_l[128*33];
  __shared__ float rhs_l[128*33];
  __shared__ float part_l[8*33];
  __shared__ float mu_l[TB];
  __shared__ float h_l[128];
  const int t=threadIdx.x, g=t>>5, bl=t&31;
  const int b = blockIdx.x*TB + bl;
  if (t<128) h_l[t]=h[t];
  __syncthreads();
  float sv[16], lv[16], rpv[16];
  float prod=0.f;
  #pragma unroll
  for (int q=0;q<16;++q){
    int i = g + 8*q;
    float s = S[i*B_TOT+b], l = LAM[i*B_TOT+b], gz = GZ[i*B_TOT+b];
    sv[q]=s; lv[q]=l; rpv[q]=gz+s-h_l[i];
    prod += s*l;
  }
  part_l[g*33+bl] = prod;
  __syncthreads();
  if (g==0){
    float m=0.f;
    #pragma unroll
    for (int q=0;q<8;++q) m += part_l[q*33+bl];
    mu_l[bl] = m*(1.f/128.f);
  }
  __syncthreads();
  const float mu = mu_l[bl];
  #pragma unroll
  for (int q=0;q<16;++q){
    int i=g+8*q;
    float rc = sv[q]*lv[q] - 0.1f*mu;
    wm_l[i*33+bl] = (rc - lv[q]*rpv[q])/sv[q] - lv[q];
  }
  __syncthreads();
  const int r0 = g*16;
  float acc[16];
  #pragma unroll
  for (int q=0;q<16;++q) acc[q] = -(QZ[(r0+q)*B_TOT+b] + Pt[(r0+q)*B_TOT+b]);
  #pragma unroll 2
  for (int j=0;j<128;++j){
    float wmv = wm_l[j*33+bl];
    const float4* gp = (const float4*)&G[j*128+r0];
    #pragma unroll
    for (int q4=0;q4<4;++q4){
      float4 gv = gp[q4];
      acc[4*q4+0]=fmaf(gv.x,wmv,acc[4*q4+0]);
      acc[4*q4+1]=fmaf(gv.y,wmv,acc[4*q4+1]);
      acc[4*q4+2]=fmaf(gv.z,wmv,acc[4*q4+2]);
      acc[4*q4+3]=fmaf(gv.w,wmv,acc[4*q4+3]);
    }
  }
  #pragma unroll
  for (int q=0;q<16;++q){
    rhs_l[(r0+q)*33+bl]=acc[q];
    RHS[(r0+q)*B_TOT+b]=acc[q];
  }
  __syncthreads();
  #pragma unroll
  for (int q=0;q<16;++q) acc[q]=0.f;
  #pragma unroll 2
  for (int j=0;j<128;++j){
    float rv = rhs_l[j*33+bl];
    const float4* mp = (const float4*)&M1[j*128+r0];
    #pragma unroll
    for (int q4=0;q4<4;++q4){
      float4 mv = mp[q4];
      acc[4*q4+0]=fmaf(mv.x,rv,acc[4*q4+0]);
      acc[4*q4+1]=fmaf(mv.y,rv,acc[4*q4+1]);
      acc[4*q4+2]=fmaf(mv.z,rv,acc[4*q4+2]);
      acc[4*q4+3]=fmaf(mv.w,rv,acc[4*q4+3]);
    }
  }
  #pragma unroll
  for (int q=0;q<16;++q) TV[(r0+q)*B_TOT+b]=acc[q];
}

// ---- k_C: 128 thr/batch, pipelined GJ || deferred trailing ----
__global__ __launch_bounds__(128) void k_C(const float* __restrict__ K,
    const float* __restrict__ Kd, const float* __restrict__ h,
    const float* __restrict__ TV,
    float* __restrict__ S, float* __restrict__ LAM, float* __restrict__ GZ,
    float* __restrict__ Y, float* __restrict__ ALPHA){
  __shared__ __align__(16) float tri[TRI_SZ];
  __shared__ float scl_l[128];
  __shared__ float sh_t[128];
  __shared__ float red[2];
  const int t = threadIdx.x, b = blockIdx.x;
  const int lane = t&63, wid = t>>6;
  float s_t=S[t*B_TOT+b], l_t=LAM[t*B_TOT+b], g_t=GZ[t*B_TOT+b];
  float rp_t = g_t + s_t - h[t];
  float prod = s_t*l_t;
  #pragma unroll
  for (int o=32;o>0;o>>=1) prod += __shfl_xor(prod,o,64);
  if (lane==0) red[wid]=prod;
  __syncthreads();
  const float mu = (red[0]+red[1])*(1.f/128.f);
  float rc_t = s_t*l_t - 0.1f*mu;
  float di_t = fminf(s_t/l_t, 1e30f);
  float sc_t = rsqrtf(Kd[t]+di_t);
  scl_l[t]=sc_t;
  sh_t[t]=TV[t*B_TOT+b]*sc_t;
  __syncthreads();
  // build equilibrated triangle (unit diag)
  #pragma unroll 4
  for (int i=0;i<128;++i){
    if (t<=i) tri[rowStart(i)+t] = (t==i)?1.f : K[i*128+t]*scl_l[i]*sc_t;
  }
  __syncthreads();
  // factorization: per phase kb:
  //  A: GJ(kb) on wave0 || REST of trailing(kb-1) on wave1 (+wave0 tail)
  //  B: panel solve (all threads)
  //  C: eager next-diag D(kb) update (4x4 tiles, threads 0..9)
  for (int kb=0;kb<8;++kb){
    const int c0=16*kb;
    // --- step A ---
    {
      int ntile=3, n1=3;
      if (kb>0){
        const int T = (128-c0)>>3;
        ntile = (T*(T+1))>>1;
        n1 = 3 + (((ntile-3)*3)>>2);      // wave1 takes 75% of REST
      }
      if (wid==0){
        chol_diag_gj(tri, c0, lane);
        if (kb>0){
          const int pc0 = c0-16;
          for (int idx=n1+lane; idx<ntile; idx+=64){
            int I = rowOfIdx(idx);
            int J = idx - ROFF(I);
            trail_tile8(tri, pc0, c0+8*I, c0+8*J, I==J);
          }
        }
      } else {
        if (kb>0){
          const int pc0 = c0-16;
          for (int idx=3+lane; idx<n1; idx+=64){
            int I = rowOfIdx(idx);
            int J = idx - ROFF(I);
            trail_tile8(tri, pc0, c0+8*I, c0+8*J, I==J);
          }
        }
      }
    }
    __syncthreads();
    // --- step B: panel ---
    const int rem = 112-c0;
    if (t<rem) panel_row(tri, c0, c0+16+t);
    __syncthreads();
    // --- step C: eager D = (c0+16 .. c0+32)^2 lower, 4x4 tiles ---
    if (kb<7 && t<10){
      int I = rowOfIdx(t);
      int J = t - ROFF(I);
      trail_tile4(tri, c0, c0+16+4*I, c0+16+4*J);
    }
    __syncthreads();
  }
  tri_solve_w2(tri, sh_t, t);
  float y = sh_t[t]*sc_t;
  float gd = di_t*y;                     // G dz = Dinv .* y (Woodbury identity)
  float ds = -rp_t - gd;
  float dl = (-rc_t - l_t*ds)/s_t;
  float ra = 1e9f;
  if (ds<0.f) ra = -s_t/ds;
  if (dl<0.f) ra = fminf(ra,-l_t/dl);
  #pragma unroll
  for (int o=32;o>0;o>>=1) ra = fminf(ra,__shfl_xor(ra,o,64));
  __syncthreads();
  if (lane==0) red[wid]=ra;
  __syncthreads();
  const float alpha = fminf(1.0f, 0.99f*fminf(red[0],red[1]));
  S[t*B_TOT+b]   = s_t + alpha*ds;
  LAM[t*B_TOT+b] = l_t + alpha*dl;
  GZ[t*B_TOT+b]  = g_t + alpha*gd;
  Y[t*B_TOT+b]   = y;
  if (t==0) ALPHA[b]=alpha;
}

// ---- k_DB: fused k_D(iter i) + k_B(iter i+1) ----
__global__ __launch_bounds__(256) void k_DB(const float* __restrict__ G,
    const float* __restrict__ Qi, const float* __restrict__ M1,
    const float* __restrict__ Pt, const float* __restrict__ h,
    const float* __restrict__ S, const float* __restrict__ LAM,
    const float* __restrict__ GZ,
    const float* __restrict__ Y, const float* __restrict__ ALPHA,
    float* __restrict__ Zst, float* __restrict__ QZ,
    float* __restrict__ RHS, float* __restrict__ TV){
  __shared__ float bufA[128*33];   // y -> qz_new -> rhs_new
  __shared__ float bufB[128*33];   // v -> wm
  __shared__ float part_l[8*33];
  __shared__ float mu_l[TB];
  __shared__ float h_l[128];
  const int t=threadIdx.x, g=t>>5, bl=t&31;
  const int b = blockIdx.x*TB + bl;
  const int r0 = g*16;
  if (t<128) h_l[t]=h[t];
  #pragma unroll
  for (int q=0;q<16;++q){
    int i=g+8*q;
    bufA[i*33+bl] = Y[i*B_TOT+b];
  }
  const float alpha = ALPHA[b];
  __syncthreads();
  // ---- part 1: v = RHS - G^T y ----
  float acc[16];
  #pragma unroll
  for (int q=0;q<16;++q) acc[q]=RHS[(r0+q)*B_TOT+b];
  #pragma unroll 2
  for (int j=0;j<128;++j){
    float yv = bufA[j*33+bl];
    const float4* gp=(const float4*)&G[j*128+r0];
    #pragma unroll
    for (int q4=0;q4<4;++q4){
      float4 gv=gp[q4];
      acc[4*q4+0]=fmaf(-gv.x,yv,acc[4*q4+0]);
      acc[4*q4+1]=fmaf(-gv.y,yv,acc[4*q4+1]);
      acc[4*q4+2]=fmaf(-gv.z,yv,acc[4*q4+2]);
      acc[4*q4+3]=fmaf(-gv.w,yv,acc[4*q4+3]);
    }
  }
  __syncthreads();   // all reads of bufA(y) done
  #pragma unroll
  for (int q=0;q<16;++q){
    const int i=r0+q;
    float qz_new = QZ[i*B_TOT+b] + alpha*acc[q];   // qz += a*v (Q dz == v)
    QZ[i*B_TOT+b] = qz_new;
    bufB[i*33+bl] = acc[q];                        // v
    bufA[i*33+bl] = qz_new;
  }
  __syncthreads();
  // ---- dz = Qi v ; z += a dz ----
  #pragma unroll
  for (int q=0;q<16;++q) acc[q]=0.f;
  #pragma unroll 2
  for (int j=0;j<128;++j){
    float vv = bufB[j*33+bl];
    const float4* qp4=(const float4*)&Qi[j*128+r0];
    #pragma unroll
    for (int q4=0;q4<4;++q4){
      float4 qv=qp4[q4];
      acc[4*q4+0]=fmaf(qv.x,vv,acc[4*q4+0]);
      acc[4*q4+1]=fmaf(qv.y,vv,acc[4*q4+1]);
      acc[4*q4+2]=fmaf(qv.z,vv,acc[4*q4+2]);
      acc[4*q4+3]=fmaf(qv.w,vv,acc[4*q4+3]);
    }
  }
  #pragma unroll
  for (int q=0;q<16;++q){
    float* zp=&Zst[(r0+q)*B_TOT+b];
    *zp = *zp + alpha*acc[q];
  }
  __syncthreads();   // all reads of bufB(v) done
  // ---- part 2: k_B stage1 (post-k_C state) ----
  float sv[16], lv[16], rpv[16];
  float prod=0.f;
  #pragma unroll
  for (int q=0;q<16;++q){
    int i = g + 8*q;
    float s = S[i*B_TOT+b], l = LAM[i*B_TOT+b], gz = GZ[i*B_TOT+b];
    sv[q]=s; lv[q]=l; rpv[q]=gz+s-h_l[i];
    prod += s*l;
  }
  part_l[g*33+bl] = prod;
  __syncthreads();
  if (g==0){
    float m=0.f;
    #pragma unroll
    for (int q=0;q<8;++q) m += part_l[q*33+bl];
    mu_l[bl] = m*(1.f/128.f);
  }
  __syncthreads();
  const float mu = mu_l[bl];
  #pragma unroll
  for (int q=0;q<16;++q){
    int i=g+8*q;
    float rc = sv[q]*lv[q] - 0.1f*mu;
    bufB[i*33+bl] = (rc - lv[q]*rpv[q])/sv[q] - lv[q];   // wm
  }
  __syncthreads();
  // ---- rhs = -(qz_new + p) + G^T wm ----
  #pragma unroll
  for (int q=0;q<16;++q) acc[q] = -(bufA[(r0+q)*33+bl] + Pt[(r0+q)*B_TOT+b]);
  #pragma unroll 2
  for (int j=0;j<128;++j){
    float wmv = bufB[j*33+bl];
    const float4* gp = (const float4*)&G[j*128+r0];
    #pragma unroll
    for (int q4=0;q4<4;++q4){
      float4 gv = gp[q4];
      acc[4*q4+0]=fmaf(gv.x,wmv,acc[4*q4+0]);
      acc[4*q4+1]=fmaf(gv.y,wmv,acc[4*q4+1]);
      acc[4*q4+2]=fmaf(gv.z,wmv,acc[4*q4+2]);
      acc[4*q4+3]=fmaf(gv.w,wmv,acc[4*q4+3]);
    }
  }
  __syncthreads();   // wm reads done; bufA own-slot overwrite safe
  #pragma unroll
  for (int q=0;q<16;++q){
    RHS[(r0+q)*B_TOT+b]=acc[q];
    bufA[(r0+q)*33+bl]=acc[q];
  }
  __syncthreads();
  // ---- tv = G Qi rhs (via M1^T) ----
  #pragma unroll
  for (int q=0;q<16;++q) acc[q]=0.f;
  #pragma unroll 2
  for (int j=0;j<128;++j){
    float rv = bufA[j*33+bl];
    const float4* mp = (const float4*)&M1[j*128+r0];
    #pragma unroll
    for (int q4=0;q4<4;++q4){
      float4 mv = mp[q4];
      acc[4*q4+0]=fmaf(mv.x,rv,acc[4*q4+0]);
      acc[4*q4+1]=fmaf(mv.y,rv,acc[4*q4+1]);
      acc[4*q4+2]=fmaf(mv.z,rv,acc[4*q4+2]);
      acc[4*q4+3]=fmaf(mv.w,rv,acc[4*q4+3]);
    }
  }
  #pragma unroll
  for (int q=0;q<16;++q) TV[(r0+q)*B_TOT+b]=acc[q];
}

// ---- k_D: final iteration tail (v, dz, z, qz) ----
__global__ __launch_bounds__(256) void k_D(const float* __restrict__ G,
    const float* __restrict__ Qi, const float* __restrict__ RHS,
    const float* __restrict__ Y, const float* __restrict__ ALPHA,
    float* __restrict__ Zst, float* __restrict__ QZ){
  __shared__ float y_l[128*33];
  __shared__ float v_l[128*33];
  const int t=threadIdx.x, g=t>>5, bl=t&31;
  const int b = blockIdx.x*TB + bl;
  #pragma unroll
  for (int q=0;q<16;++q){
    int i=g+8*q;
    y_l[i*33+bl] = Y[i*B_TOT+b];
  }
  const float alpha = ALPHA[b];
  __syncthreads();
  const int r0=g*16;
  float acc[16];
  #pragma unroll
  for (int q=0;q<16;++q) acc[q]=RHS[(r0+q)*B_TOT+b];
  #pragma unroll 2
  for (int j=0;j<128;++j){
    float yv = y_l[j*33+bl];
    const float4* gp=(const float4*)&G[j*128+r0];
    #pragma unroll
    for (int q4=0;q4<4;++q4){
      float4 gv=gp[q4];
      acc[4*q4+0]=fmaf(-gv.x,yv,acc[4*q4+0]);
      acc[4*q4+1]=fmaf(-gv.y,yv,acc[4*q4+1]);
      acc[4*q4+2]=fmaf(-gv.z,yv,acc[4*q4+2]);
      acc[4*q4+3]=fmaf(-gv.w,yv,acc[4*q4+3]);
    }
  }
  #pragma unroll
  for (int q=0;q<16;++q){
    v_l[(r0+q)*33+bl]=acc[q];
    float* qp=&QZ[(r0+q)*B_TOT+b];
    *qp = *qp + alpha*acc[q];
  }
  __syncthreads();
  #pragma unroll
  for (int q=0;q<16;++q) acc[q]=0.f;
  #pragma unroll 2
  for (int j=0;j<128;++j){
    float vv = v_l[j*33+bl];
    const float4* qp4=(const float4*)&Qi[j*128+r0];
    #pragma unroll
    for (int q4=0;q4<4;++q4){
      float4 qv=qp4[q4];
      acc[4*q4+0]=fmaf(qv.x,vv,acc[4*q4+0]);
      acc[4*q4+1]=fmaf(qv.y,vv,acc[4*q4+1]);
      acc[4*q4+2]=fmaf(qv.z,vv,acc[4*q4+2]);
      acc[4*q4+3]=fmaf(qv.w,vv,acc[4*q4+3]);
    }
  }
  #pragma unroll
  for (int q=0;q<16;++q){
    float* zp=&Zst[(r0+q)*B_TOT+b];
    *zp = *zp + alpha*acc[q];
  }
}

// out = log_softmax(Z.reshape(10, 32768), axis=1), Z stored n-major [i][B]
__global__ __launch_bounds__(1024) void k_logsoftmax(const float* __restrict__ Zst,
                                                     float* __restrict__ out){
  __shared__ float red[16];
  __shared__ float sval[2];
  const int r = blockIdx.x, t = threadIdx.x;
  float m = -1e30f;
  for (int k=t;k<32768;k+=1024){
    float v = Zst[(k&127)*B_TOT + r*256 + (k>>7)];
    m = fmaxf(m, v);
  }
  #pragma unroll
  for (int o=32;o>0;o>>=1) m = fmaxf(m, __shfl_down(m,o,64));
  if ((t&63)==0) red[t>>6] = m;
  __syncthreads();
  if (t==0){ float mm=red[0]; for (int w=1;w<16;++w) mm=fmaxf(mm,red[w]); sval[0]=mm; }
  __syncthreads();
  const float mx = sval[0];
  float s=0.f;
  for (int k=t;k<32768;k+=1024){
    float v = Zst[(k&127)*B_TOT + r*256 + (k>>7)];
    s += expf(v-mx);
  }
  #pragma unroll
  for (int o=32;o>0;o>>=1) s += __shfl_down(s,o,64);
  if ((t&63)==0) red[t>>6]=s;
  __syncthreads();
  if (t==0){ float ss=0.f; for (int w=0;w<16;++w) ss+=red[w]; sval[1]=logf(ss); }
  __syncthreads();
  const float lse = sval[1];
  for (int k=t;k<32768;k+=1024){
    float v = Zst[(k&127)*B_TOT + r*256 + (k>>7)];
    out[(size_t)r*32768+k] = v-mx-lse;
  }
}

extern "C" void kernel_launch(void* const* d_in, const int* in_sizes, int n_in,
                              void* d_out, int out_size, void* d_ws, size_t ws_size,
                              hipStream_t stream){
  // inputs: 0=x (unused), 1=Q[128x128], 2=p[2560x128], 3=G[128x128], 4=h[128], 5=m
  const float* Q = (const float*)d_in[1];
  const float* p = (const float*)d_in[2];
  const float* G = (const float*)d_in[3];
  const float* h = (const float*)d_in[4];
  float* ws  = (float*)d_ws;
  const int NE = 128*B_TOT;
  float* Zst = ws;                       // NE
  float* Qi  = Zst + NE;                 // 16384
  float* M1  = Qi + 16384;
  float* K   = M1 + 16384;
  float* Kd  = K + 16384;                // 128
  float* ALPHA = Kd + 128;               // 2560
  float* Pt  = ALPHA + 2560;             // NE
  float* S   = Pt + NE;
  float* LAM = S + NE;
  float* GZ  = LAM + NE;
  float* QZ  = GZ + NE;
  float* RHS = QZ + NE;
  float* TV  = RHS + NE;
  float* Y   = TV + NE;
  float* TRIQ= Y + NE;                   // 8448
  float* out = (float*)d_out;

  hipLaunchKernelGGL(k_prepA, dim3(1), dim3(256), 0, stream, Q, TRIQ);
  hipLaunchKernelGGL(k_prepB, dim3(8), dim3(256), 0, stream, TRIQ, G, Qi, M1);
  hipLaunchKernelGGL(k_kmat, dim3(64), dim3(256), 0, stream, G, M1, K, Kd);
  hipLaunchKernelGGL(k_init, dim3((NE+255)/256), dim3(256), 0, stream,
                     p, Pt, S, LAM, GZ, QZ, Zst);
  hipLaunchKernelGGL(k_B, dim3(NB), dim3(256), 0, stream,
                     G, M1, Pt, h, S, LAM, GZ, QZ, RHS, TV);
  for (int it=0; it<20; ++it){
    hipLaunchKernelGGL(k_C, dim3(B_TOT), dim3(128), 0, stream,
                       K, Kd, h, TV, S, LAM, GZ, Y, ALPHA);
    if (it < 19){
      hipLaunchKernelGGL(k_DB, dim3(NB), dim3(256), 0, stream,
                         G, Qi, M1, Pt, h, S, LAM, GZ, Y, ALPHA,
                         Zst, QZ, RHS, TV);
    } else {
      hipLaunchKernelGGL(k_D, dim3(NB), dim3(256), 0, stream,
                         G, Qi, RHS, Y, ALPHA, Zst, QZ);
    }
  }
  hipLaunchKernelGGL(k_logsoftmax, dim3(10), dim3(1024), 0, stream, Zst, out);
}

// Round 11
// 8088.603 us; speedup vs baseline: 1.9182x; 1.4985x over previous
//
#include <hip/hip_runtime.h>
#include <math.h>

// OptNet IPM QP solve via Woodbury, Round 11: best-of composition.
//  M = Q + G^T D G;  M^{-1} = Qi - Qi G^T (Dinv + K)^{-1} G Qi,  K = G Qi G^T
// k_C = round-7 structure exactly (wave0 GJ, one-pass panel, 4x4 trailing;
// float4-RMW tiles, low VGPR). Round-10's k_C pipelining regressed (VGPR 176,
// imbalanced waves, extra barriers) and is dropped. Kept from round 10:
// k_DB fusion (k_D(i)+k_B(i+1), 74us vs 137us), split prep, final k_D.

#define B_TOT 2560
#define TB 32
#define NB (B_TOT/TB)

__device__ __forceinline__ int ROFF(int i){ return (i*(i+1))>>1; }
// padded-row packed lower triangle: row i starts at rowStart(i), 16B aligned
__device__ __forceinline__ int rowStart(int i){
  int a=i>>2, b=i&3;
  return ((a+1)*((a<<1)+b))<<2;
}
#define TRI_SZ 8448

__device__ __forceinline__ int rowOfIdx(int idx){
  int i = (int)((sqrtf(8.f*(float)idx+1.f)-1.f)*0.5f);
  while (((i+1)*(i+2)>>1) <= idx) ++i;
  while (((i*(i+1))>>1) > idx) --i;
  return i;
}

// ---- Gauss-Jordan 16x16 diag block: factor AND invert (lanes 0..15 of one wave)
// On exit diag slots hold Linv (lower). ----
__device__ __forceinline__ void chol_diag_gj(float* tri, int c0, int lane){
  float rowA[16], rowW[16];
  const int r = lane;
  #pragma unroll
  for (int j=0;j<16;++j){ rowA[j]=0.f; rowW[j]=0.f; }
  if (r < 16){
    const float* src = &tri[rowStart(c0+r)+c0];
    #pragma unroll
    for (int q=0;q<4;++q){
      if (q <= (r>>2)){
        float4 w = *(const float4*)&src[4*q];
        rowA[4*q+0]=w.x; rowA[4*q+1]=w.y; rowA[4*q+2]=w.z; rowA[4*q+3]=w.w;
      }
    }
    #pragma unroll
    for (int j=0;j<16;++j) if (j>r) rowA[j]=0.f;
    #pragma unroll
    for (int j=0;j<16;++j) rowW[j] = (j==r)?1.f:0.f;
  }
  #pragma unroll
  for (int k=0;k<16;++k){
    float akk = __shfl(rowA[k], k, 64);
    akk = fmaxf(akk, 1e-12f);
    float linv = rsqrtf(akk);
    float lrk = rowA[k]*linv;
    if (r==k){
      #pragma unroll
      for (int c=0;c<16;++c) rowW[c] *= linv;
    }
    #pragma unroll
    for (int j=k+1;j<16;++j){
      float ljk = __shfl(lrk, j, 64);
      if (r>=j) rowA[j] = fmaf(-lrk, ljk, rowA[j]);
    }
    #pragma unroll
    for (int c=0;c<=k;++c){
      float wkc = __shfl(rowW[c], k, 64);
      if (r>k) rowW[c] = fmaf(-lrk, wkc, rowW[c]);
    }
  }
  if (r < 16){
    float* dst = &tri[rowStart(c0+r)+c0];
    #pragma unroll
    for (int q=0;q<4;++q){
      if (q <= (r>>2)){
        float4 w; w.x=rowW[4*q+0]; w.y=rowW[4*q+1]; w.z=rowW[4*q+2]; w.w=rowW[4*q+3];
        *(float4*)&dst[4*q] = w;
      }
    }
  }
}

// ---- 8x8 trailing tile (k_prepA only) ----
__device__ __forceinline__ void trail_tile8(float* tri, int pc0, int i0, int j0,
                                            bool diag){
  float4 Pi[8][4], Pj[8][4];
  #pragma unroll
  for (int ii=0;ii<8;++ii){
    const float* rp = &tri[rowStart(i0+ii)+pc0];
    #pragma unroll
    for (int q=0;q<4;++q) Pi[ii][q] = *(const float4*)&rp[4*q];
  }
  #pragma unroll
  for (int jj=0;jj<8;++jj){
    const float* rp = &tri[rowStart(j0+jj)+pc0];
    #pragma unroll
    for (int q=0;q<4;++q) Pj[jj][q] = *(const float4*)&rp[4*q];
  }
  float acc[8][8];
  #pragma unroll
  for (int ii=0;ii<8;++ii)
    #pragma unroll
    for (int jj=0;jj<8;++jj) acc[ii][jj]=0.f;
  #pragma unroll
  for (int q=0;q<4;++q){
    #pragma unroll
    for (int ii=0;ii<8;++ii){
      #pragma unroll
      for (int jj=0;jj<8;++jj){
        acc[ii][jj] = fmaf(Pi[ii][q].x, Pj[jj][q].x, acc[ii][jj]);
        acc[ii][jj] = fmaf(Pi[ii][q].y, Pj[jj][q].y, acc[ii][jj]);
        acc[ii][jj] = fmaf(Pi[ii][q].z, Pj[jj][q].z, acc[ii][jj]);
        acc[ii][jj] = fmaf(Pi[ii][q].w, Pj[jj][q].w, acc[ii][jj]);
      }
    }
  }
  if (!diag){
    #pragma unroll
    for (int ii=0;ii<8;++ii){
      float4* p = (float4*)&tri[rowStart(i0+ii)+j0];
      float4 v0=p[0], v1=p[1];
      v0.x-=acc[ii][0]; v0.y-=acc[ii][1]; v0.z-=acc[ii][2]; v0.w-=acc[ii][3];
      v1.x-=acc[ii][4]; v1.y-=acc[ii][5]; v1.z-=acc[ii][6]; v1.w-=acc[ii][7];
      p[0]=v0; p[1]=v1;
    }
  } else {
    #pragma unroll
    for (int ii=0;ii<8;++ii){
      float4* p = (float4*)&tri[rowStart(i0+ii)+j0];
      const int nq = (ii>>2)+1;
      #pragma unroll
      for (int q=0;q<2;++q){
        if (q<nq){
          float4 v=p[q];
          v.x-=acc[ii][4*q+0]; v.y-=acc[ii][4*q+1];
          v.z-=acc[ii][4*q+2]; v.w-=acc[ii][4*q+3];
          p[q]=v;
        }
      }
    }
  }
}

// ---- 4x4 trailing tile (k_C): float4 RMW; diag-tile pad writes are benign ----
__device__ __forceinline__ void trail_tile4(float* tri, int pc0, int i0, int j0){
  float4 Pi[4][4], Pj[4][4];
  #pragma unroll
  for (int ii=0;ii<4;++ii){
    const float* rp = &tri[rowStart(i0+ii)+pc0];
    #pragma unroll
    for (int q=0;q<4;++q) Pi[ii][q] = *(const float4*)&rp[4*q];
  }
  #pragma unroll
  for (int jj=0;jj<4;++jj){
    const float* rp = &tri[rowStart(j0+jj)+pc0];
    #pragma unroll
    for (int q=0;q<4;++q) Pj[jj][q] = *(const float4*)&rp[4*q];
  }
  float acc[4][4];
  #pragma unroll
  for (int ii=0;ii<4;++ii)
    #pragma unroll
    for (int jj=0;jj<4;++jj) acc[ii][jj]=0.f;
  #pragma unroll
  for (int q=0;q<4;++q){
    #pragma unroll
    for (int ii=0;ii<4;++ii){
      #pragma unroll
      for (int jj=0;jj<4;++jj){
        acc[ii][jj] = fmaf(Pi[ii][q].x, Pj[jj][q].x, acc[ii][jj]);
        acc[ii][jj] = fmaf(Pi[ii][q].y, Pj[jj][q].y, acc[ii][jj]);
        acc[ii][jj] = fmaf(Pi[ii][q].z, Pj[jj][q].z, acc[ii][jj]);
        acc[ii][jj] = fmaf(Pi[ii][q].w, Pj[jj][q].w, acc[ii][jj]);
      }
    }
  }
  #pragma unroll
  for (int ii=0;ii<4;++ii){
    float4* p = (float4*)&tri[rowStart(i0+ii)+j0];
    float4 v=p[0];
    v.x-=acc[ii][0]; v.y-=acc[ii][1]; v.z-=acc[ii][2]; v.w-=acc[ii][3];
    p[0]=v;
  }
}

// ---- panel solve row: X = A * Linv^T (one row) ----
__device__ __forceinline__ void panel_row(float* tri, int c0, int r){
  const int rb = rowStart(r)+c0;
  float a[16];
  #pragma unroll
  for (int q=0;q<4;++q){
    float4 w = *(const float4*)&tri[rb+4*q];
    a[4*q+0]=w.x; a[4*q+1]=w.y; a[4*q+2]=w.z; a[4*q+3]=w.w;
  }
  float x[16];
  #pragma unroll
  for (int c=0;c<16;++c){
    float acc=0.f;
    const int lb = rowStart(c0+c)+c0;
    #pragma unroll
    for (int q=0;q<=(c>>2);++q){
      float4 w = *(const float4*)&tri[lb+4*q];
      if (4*q+0<=c) acc = fmaf(w.x, a[4*q+0], acc);
      if (4*q+1<=c) acc = fmaf(w.y, a[4*q+1], acc);
      if (4*q+2<=c) acc = fmaf(w.z, a[4*q+2], acc);
      if (4*q+3<=c) acc = fmaf(w.w, a[4*q+3], acc);
    }
    x[c]=acc;
  }
  #pragma unroll
  for (int q=0;q<4;++q){
    float4 w; w.x=x[4*q+0]; w.y=x[4*q+1]; w.z=x[4*q+2]; w.w=x[4*q+3];
    *(float4*)&tri[rb+4*q] = w;
  }
}

// ---- 256-thread blocked Cholesky (k_prepA only) ----
__device__ void chol_factor(float* tri, int t, int lane, int wid){
  for (int kb=0; kb<8; ++kb){
    const int c0 = kb*16;
    if (wid==(kb&3)) chol_diag_gj(tri, c0, lane);
    __syncthreads();
    const int rem = 112 - c0;
    if (t < rem) panel_row(tri, c0, c0+16+t);
    __syncthreads();
    if (rem > 0){
      const int base = c0+16;
      const int T = rem>>3;
      const int ntile = (T*(T+1))>>1;
      for (int idx=t; idx<ntile; idx+=256){
        int I = rowOfIdx(idx);
        int J = idx - ROFF(I);
        trail_tile8(tri, c0, base+8*I, base+8*J, I==J);
      }
    }
    __syncthreads();
  }
}

// ---- 128-thread blocked Cholesky (k_C, round-7 structure) ----
__device__ void chol_factor_w2(float* tri, int t, int lane, int wid){
  for (int kb=0; kb<8; ++kb){
    const int c0 = kb*16;
    if (wid==0) chol_diag_gj(tri, c0, lane);
    __syncthreads();
    const int rem = 112 - c0;
    if (t < rem) panel_row(tri, c0, c0+16+t);
    __syncthreads();
    if (rem > 0){
      const int base = c0+16;
      const int R = rem>>2;
      const int ntile = (R*(R+1))>>1;
      for (int idx=t; idx<ntile; idx+=128){
        int I = rowOfIdx(idx);
        int J = idx - ROFF(I);
        trail_tile4(tri, c0, base+4*I, base+4*J);
      }
    }
    __syncthreads();
  }
}

// 128-thread forward/backward solve; diag slots hold Linv; rhs in LDS
__device__ void tri_solve_w2(const float* tri, float* rhs, int t){
  for (int kb=0;kb<8;++kb){
    const int c0=kb*16;
    if (t<16){
      const int c=t;
      const float* lrow = &tri[rowStart(c0+c)+c0];
      float acc=0.f;
      #pragma unroll
      for (int cp=0;cp<16;++cp) if (cp<=c) acc = fmaf(lrow[cp], rhs[c0+cp], acc);
      rhs[c0+c] = acc;
    }
    __syncthreads();
    const int rem = 112-c0;
    if (t<rem){
      const int r = c0+16+t;
      const int rb = rowStart(r)+c0;
      float acc = rhs[r];
      #pragma unroll
      for (int q=0;q<4;++q){
        float4 w = *(const float4*)&tri[rb+4*q];
        acc = fmaf(-w.x, rhs[c0+4*q+0], acc);
        acc = fmaf(-w.y, rhs[c0+4*q+1], acc);
        acc = fmaf(-w.z, rhs[c0+4*q+2], acc);
        acc = fmaf(-w.w, rhs[c0+4*q+3], acc);
      }
      rhs[r] = acc;
    }
    __syncthreads();
  }
  for (int kb=7;kb>=0;--kb){
    const int c0=kb*16;
    if (t<16){
      const int c=t;
      float acc=0.f;
      #pragma unroll
      for (int cp=0;cp<16;++cp)
        if (cp>=c) acc = fmaf(tri[rowStart(c0+cp)+c0+c], rhs[c0+cp], acc);
      rhs[c0+c] = acc;
    }
    __syncthreads();
    if (t<c0){
      float acc = rhs[t];
      #pragma unroll
      for (int c=0;c<16;++c) acc = fmaf(-tri[rowStart(c0+c)+t], rhs[c0+c], acc);
      rhs[t]=acc;
    }
    __syncthreads();
  }
}

// ---- k_prepA: factor chol(Q), dump triangle to global ----
__global__ __launch_bounds__(256) void k_prepA(const float* __restrict__ Q,
                                               float* __restrict__ TRIQ){
  __shared__ __align__(16) float tri[TRI_SZ];
  const int t = threadIdx.x;
  const int lane = t&63, wid = t>>6;
  for (int idx=t; idx<8256; idx+=256){
    int i = rowOfIdx(idx); int j = idx - ROFF(i);
    tri[rowStart(i)+j] = Q[i*128+j];
  }
  __syncthreads();
  chol_factor(tri, t, lane, wid);
  for (int idx=t; idx<TRI_SZ; idx+=256) TRIQ[idx]=tri[idx];
}

// ---- k_prepB: 8 blocks, each one 32-col solve chunk -> Qi or M1 ----
__global__ __launch_bounds__(256) void k_prepB(const float* __restrict__ TRIQ,
        const float* __restrict__ Gm, float* __restrict__ Qi, float* __restrict__ M1)
{
  __shared__ __align__(16) float tri[TRI_SZ];
  __shared__ float Xl[128*32];
  const int t = threadIdx.x, cc = blockIdx.x;
  const int a0 = (cc&3)*32;
  const bool ident = (cc<4);
  for (int idx=t; idx<TRI_SZ; idx+=256) tri[idx]=TRIQ[idx];
  for (int idx=t; idx<4096; idx+=256){
    int i=idx>>5, j=idx&31;
    Xl[idx] = ident ? ((i==(a0+j))?1.f:0.f) : Gm[(a0+j)*128+i];
  }
  __syncthreads();
  for (int kb=0;kb<8;++kb){                    // forward: X := L^{-1} X
    const int c0=kb*16;
    if (t<32){
      float v[16], x[16];
      #pragma unroll
      for (int c=0;c<16;++c) v[c]=Xl[(c0+c)*32+t];
      #pragma unroll
      for (int c=0;c<16;++c){
        float acc=0.f;
        const int lb=rowStart(c0+c)+c0;
        #pragma unroll
        for (int cp=0;cp<16;++cp) if (cp<=c) acc=fmaf(tri[lb+cp], v[cp], acc);
        x[c]=acc;
      }
      #pragma unroll
      for (int c=0;c<16;++c) Xl[(c0+c)*32+t]=x[c];
    }
    __syncthreads();
    const int rem=112-c0;
    for (int rr=(t>>5); rr<rem; rr+=8){
      const int r=c0+16+rr, j=t&31;
      float acc=Xl[r*32+j];
      #pragma unroll
      for (int c=0;c<16;++c) acc = fmaf(-tri[rowStart(r)+c0+c], Xl[(c0+c)*32+j], acc);
      Xl[r*32+j]=acc;
    }
    __syncthreads();
  }
  for (int kb=7;kb>=0;--kb){                   // backward: X := L^{-T} X
    const int c0=kb*16;
    if (t<32){
      float v[16], x[16];
      #pragma unroll
      for (int c=0;c<16;++c) v[c]=Xl[(c0+c)*32+t];
      #pragma unroll
      for (int c=0;c<16;++c){
        float acc=0.f;
        #pragma unroll
        for (int cp=0;cp<16;++cp) if (cp>=c) acc=fmaf(tri[rowStart(c0+cp)+c0+c], v[cp], acc);
        x[c]=acc;
      }
      #pragma unroll
      for (int c=0;c<16;++c) Xl[(c0+c)*32+t]=x[c];
    }
    __syncthreads();
    for (int rr=(t>>5); rr<c0; rr+=8){
      const int j=t&31;
      float acc=Xl[rr*32+j];
      #pragma unroll
      for (int c=0;c<16;++c) acc = fmaf(-tri[rowStart(c0+c)+rr], Xl[(c0+c)*32+j], acc);
      Xl[rr*32+j]=acc;
    }
    __syncthreads();
  }
  float* dst = ident ? Qi : M1;
  for (int idx=t; idx<4096; idx+=256){
    int i=idx>>5, j=idx&31;
    dst[i*128+a0+j] = Xl[idx];
  }
}

__global__ __launch_bounds__(256) void k_kmat(const float* __restrict__ Gm,
        const float* __restrict__ M1, float* __restrict__ K, float* __restrict__ Kd){
  const int idx = blockIdx.x*256 + threadIdx.x;
  const int a = idx>>7, bcol = idx&127;
  float a0=0.f,a1=0.f,a2=0.f,a3=0.f;
  #pragma unroll
  for (int j=0;j<128;j+=4){
    a0 = fmaf(Gm[a*128+j+0], M1[(j+0)*128+bcol], a0);
    a1 = fmaf(Gm[a*128+j+1], M1[(j+1)*128+bcol], a1);
    a2 = fmaf(Gm[a*128+j+2], M1[(j+2)*128+bcol], a2);
    a3 = fmaf(Gm[a*128+j+3], M1[(j+3)*128+bcol], a3);
  }
  float acc = (a0+a1)+(a2+a3);
  K[idx] = acc;
  if (a==bcol) Kd[a]=acc;
}

__global__ __launch_bounds__(256) void k_init(const float* __restrict__ p,
    float* __restrict__ Pt, float* __restrict__ S, float* __restrict__ LAM,
    float* __restrict__ GZ, float* __restrict__ QZ, float* __restrict__ Zst){
  int idx = blockIdx.x*256 + threadIdx.x;
  if (idx < 128*B_TOT){
    int i = idx/B_TOT, b = idx - i*B_TOT;
    Pt[idx] = p[b*128+i];
    S[idx]=1.f; LAM[idx]=1.f; GZ[idx]=0.f; QZ[idx]=0.f; Zst[idx]=0.f;
  }
}

// ---- k_B: prologue only: stage1 + rhs + tv ----
__global__ __launch_bounds__(256) void k_B(const float* __restrict__ G,
    const float* __restrict__ M1, const float* __restrict__ Pt,
    const float* __restrict__ h,
    const float* __restrict__ S, const float* __restrict__ LAM,
    const float* __restrict__ GZ, const float* __restrict__ QZ,
    float* __restrict__ RHS, float* __restrict__ TV){
  __shared__ float wm_l[128*33];
  __shared__ float rhs_l[128*33];
  __shared__ float part_l[8*33];
  __shared__ float mu_l[TB];
  __shared__ float h_l[128];
  const int t=threadIdx.x, g=t>>5, bl=t&31;
  const int b = blockIdx.x*TB + bl;
  if (t<128) h_l[t]=h[t];
  __syncthreads();
  float sv[16], lv[16], rpv[16];
  float prod=0.f;
  #pragma unroll
  for (int q=0;q<16;++q){
    int i = g + 8*q;
    float s = S[i*B_TOT+b], l = LAM[i*B_TOT+b], gz = GZ[i*B_TOT+b];
    sv[q]=s; lv[q]=l; rpv[q]=gz+s-h_l[i];
    prod += s*l;
  }
  part_l[g*33+bl] = prod;
  __syncthreads();
  if (g==0){
    float m=0.f;
    #pragma unroll
    for (int q=0;q<8;++q) m += part_l[q*33+bl];
    mu_l[bl] = m*(1.f/128.f);
  }
  __syncthreads();
  const float mu = mu_l[bl];
  #pragma unroll
  for (int q=0;q<16;++q){
    int i=g+8*q;
    float rc = sv[q]*lv[q] - 0.1f*mu;
    wm_l[i*33+bl] = (rc - lv[q]*rpv[q])/sv[q] - lv[q];
  }
  __syncthreads();
  const int r0 = g*16;
  float acc[16];
  #pragma unroll
  for (int q=0;q<16;++q) acc[q] = -(QZ[(r0+q)*B_TOT+b] + Pt[(r0+q)*B_TOT+b]);
  #pragma unroll 2
  for (int j=0;j<128;++j){
    float wmv = wm_l[j*33+bl];
    const float4* gp = (const float4*)&G[j*128+r0];
    #pragma unroll
    for (int q4=0;q4<4;++q4){
      float4 gv = gp[q4];
      acc[4*q4+0]=fmaf(gv.x,wmv,acc[4*q4+0]);
      acc[4*q4+1]=fmaf(gv.y,wmv,acc[4*q4+1]);
      acc[4*q4+2]=fmaf(gv.z,wmv,acc[4*q4+2]);
      acc[4*q4+3]=fmaf(gv.w,wmv,acc[4*q4+3]);
    }
  }
  #pragma unroll
  for (int q=0;q<16;++q){
    rhs_l[(r0+q)*33+bl]=acc[q];
    RHS[(r0+q)*B_TOT+b]=acc[q];
  }
  __syncthreads();
  #pragma unroll
  for (int q=0;q<16;++q) acc[q]=0.f;
  #pragma unroll 2
  for (int j=0;j<128;++j){
    float rv = rhs_l[j*33+bl];
    const float4* mp = (const float4*)&M1[j*128+r0];
    #pragma unroll
    for (int q4=0;q4<4;++q4){
      float4 mv = mp[q4];
      acc[4*q4+0]=fmaf(mv.x,rv,acc[4*q4+0]);
      acc[4*q4+1]=fmaf(mv.y,rv,acc[4*q4+1]);
      acc[4*q4+2]=fmaf(mv.z,rv,acc[4*q4+2]);
      acc[4*q4+3]=fmaf(mv.w,rv,acc[4*q4+3]);
    }
  }
  #pragma unroll
  for (int q=0;q<16;++q) TV[(r0+q)*B_TOT+b]=acc[q];
}

// ---- k_C: 128 threads per batch (round-7 structure) ----
__global__ __launch_bounds__(128) void k_C(const float* __restrict__ K,
    const float* __restrict__ Kd, const float* __restrict__ h,
    const float* __restrict__ TV,
    float* __restrict__ S, float* __restrict__ LAM, float* __restrict__ GZ,
    float* __restrict__ Y, float* __restrict__ ALPHA){
  __shared__ __align__(16) float tri[TRI_SZ];
  __shared__ float scl_l[128];
  __shared__ float sh_t[128];
  __shared__ float red[2];
  const int t = threadIdx.x, b = blockIdx.x;
  const int lane = t&63, wid = t>>6;
  float s_t=S[t*B_TOT+b], l_t=LAM[t*B_TOT+b], g_t=GZ[t*B_TOT+b];
  float rp_t = g_t + s_t - h[t];
  float prod = s_t*l_t;
  #pragma unroll
  for (int o=32;o>0;o>>=1) prod += __shfl_xor(prod,o,64);
  if (lane==0) red[wid]=prod;
  __syncthreads();
  const float mu = (red[0]+red[1])*(1.f/128.f);
  float rc_t = s_t*l_t - 0.1f*mu;
  float di_t = fminf(s_t/l_t, 1e30f);
  float sc_t = rsqrtf(Kd[t]+di_t);
  scl_l[t]=sc_t;
  sh_t[t]=TV[t*B_TOT+b]*sc_t;
  __syncthreads();
  // build equilibrated triangle (unit diag): row sweep, coalesced K reads
  #pragma unroll 4
  for (int i=0;i<128;++i){
    if (t<=i) tri[rowStart(i)+t] = (t==i)?1.f : K[i*128+t]*scl_l[i]*sc_t;
  }
  __syncthreads();
  chol_factor_w2(tri, t, lane, wid);
  tri_solve_w2(tri, sh_t, t);
  float y = sh_t[t]*sc_t;
  float gd = di_t*y;                     // G dz = Dinv .* y (Woodbury identity)
  float ds = -rp_t - gd;
  float dl = (-rc_t - l_t*ds)/s_t;
  float ra = 1e9f;
  if (ds<0.f) ra = -s_t/ds;
  if (dl<0.f) ra = fminf(ra,-l_t/dl);
  #pragma unroll
  for (int o=32;o>0;o>>=1) ra = fminf(ra,__shfl_xor(ra,o,64));
  __syncthreads();
  if (lane==0) red[wid]=ra;
  __syncthreads();
  const float alpha = fminf(1.0f, 0.99f*fminf(red[0],red[1]));
  S[t*B_TOT+b]   = s_t + alpha*ds;
  LAM[t*B_TOT+b] = l_t + alpha*dl;
  GZ[t*B_TOT+b]  = g_t + alpha*gd;
  Y[t*B_TOT+b]   = y;
  if (t==0) ALPHA[b]=alpha;
}

// ---- k_DB: fused k_D(iter i) + k_B(iter i+1) ----
__global__ __launch_bounds__(256) void k_DB(const float* __restrict__ G,
    const float* __restrict__ Qi, const float* __restrict__ M1,
    const float* __restrict__ Pt, const float* __restrict__ h,
    const float* __restrict__ S, const float* __restrict__ LAM,
    const float* __restrict__ GZ,
    const float* __restrict__ Y, const float* __restrict__ ALPHA,
    float* __restrict__ Zst, float* __restrict__ QZ,
    float* __restrict__ RHS, float* __restrict__ TV){
  __shared__ float bufA[128*33];   // y -> qz_new -> rhs_new
  __shared__ float bufB[128*33];   // v -> wm
  __shared__ float part_l[8*33];
  __shared__ float mu_l[TB];
  __shared__ float h_l[128];
  const int t=threadIdx.x, g=t>>5, bl=t&31;
  const int b = blockIdx.x*TB + bl;
  const int r0 = g*16;
  if (t<128) h_l[t]=h[t];
  #pragma unroll
  for (int q=0;q<16;++q){
    int i=g+8*q;
    bufA[i*33+bl] = Y[i*B_TOT+b];
  }
  const float alpha = ALPHA[b];
  __syncthreads();
  // ---- part 1: v = RHS - G^T y ----
  float acc[16];
  #pragma unroll
  for (int q=0;q<16;++q) acc[q]=RHS[(r0+q)*B_TOT+b];
  #pragma unroll 2
  for (int j=0;j<128;++j){
    float yv = bufA[j*33+bl];
    const float4* gp=(const float4*)&G[j*128+r0];
    #pragma unroll
    for (int q4=0;q4<4;++q4){
      float4 gv=gp[q4];
      acc[4*q4+0]=fmaf(-gv.x,yv,acc[4*q4+0]);
      acc[4*q4+1]=fmaf(-gv.y,yv,acc[4*q4+1]);
      acc[4*q4+2]=fmaf(-gv.z,yv,acc[4*q4+2]);
      acc[4*q4+3]=fmaf(-gv.w,yv,acc[4*q4+3]);
    }
  }
  __syncthreads();   // all reads of bufA(y) done
  #pragma unroll
  for (int q=0;q<16;++q){
    const int i=r0+q;
    float qz_new = QZ[i*B_TOT+b] + alpha*acc[q];   // qz += a*v (Q dz == v)
    QZ[i*B_TOT+b] = qz_new;
    bufB[i*33+bl] = acc[q];                        // v
    bufA[i*33+bl] = qz_new;
  }
  __syncthreads();
  // ---- dz = Qi v ; z += a dz ----
  #pragma unroll
  for (int q=0;q<16;++q) acc[q]=0.f;
  #pragma unroll 2
  for (int j=0;j<128;++j){
    float vv = bufB[j*33+bl];
    const float4* qp4=(const float4*)&Qi[j*128+r0];
    #pragma unroll
    for (int q4=0;q4<4;++q4){
      float4 qv=qp4[q4];
      acc[4*q4+0]=fmaf(qv.x,vv,acc[4*q4+0]);
      acc[4*q4+1]=fmaf(qv.y,vv,acc[4*q4+1]);
      acc[4*q4+2]=fmaf(qv.z,vv,acc[4*q4+2]);
      acc[4*q4+3]=fmaf(qv.w,vv,acc[4*q4+3]);
    }
  }
  #pragma unroll
  for (int q=0;q<16;++q){
    float* zp=&Zst[(r0+q)*B_TOT+b];
    *zp = *zp + alpha*acc[q];
  }
  __syncthreads();   // all reads of bufB(v) done
  // ---- part 2: k_B stage1 (post-k_C state) ----
  float sv[16], lv[16], rpv[16];
  float prod=0.f;
  #pragma unroll
  for (int q=0;q<16;++q){
    int i = g + 8*q;
    float s = S[i*B_TOT+b], l = LAM[i*B_TOT+b], gz = GZ[i*B_TOT+b];
    sv[q]=s; lv[q]=l; rpv[q]=gz+s-h_l[i];
    prod += s*l;
  }
  part_l[g*33+bl] = prod;
  __syncthreads();
  if (g==0){
    float m=0.f;
    #pragma unroll
    for (int q=0;q<8;++q) m += part_l[q*33+bl];
    mu_l[bl] = m*(1.f/128.f);
  }
  __syncthreads();
  const float mu = mu_l[bl];
  #pragma unroll
  for (int q=0;q<16;++q){
    int i=g+8*q;
    float rc = sv[q]*lv[q] - 0.1f*mu;
    bufB[i*33+bl] = (rc - lv[q]*rpv[q])/sv[q] - lv[q];   // wm
  }
  __syncthreads();
  // ---- rhs = -(qz_new + p) + G^T wm ----
  #pragma unroll
  for (int q=0;q<16;++q) acc[q] = -(bufA[(r0+q)*33+bl] + Pt[(r0+q)*B_TOT+b]);
  #pragma unroll 2
  for (int j=0;j<128;++j){
    float wmv = bufB[j*33+bl];
    const float4* gp = (const float4*)&G[j*128+r0];
    #pragma unroll
    for (int q4=0;q4<4;++q4){
      float4 gv = gp[q4];
      acc[4*q4+0]=fmaf(gv.x,wmv,acc[4*q4+0]);
      acc[4*q4+1]=fmaf(gv.y,wmv,acc[4*q4+1]);
      acc[4*q4+2]=fmaf(gv.z,wmv,acc[4*q4+2]);
      acc[4*q4+3]=fmaf(gv.w,wmv,acc[4*q4+3]);
    }
  }
  __syncthreads();   // wm reads done
  #pragma unroll
  for (int q=0;q<16;++q){
    RHS[(r0+q)*B_TOT+b]=acc[q];
    bufA[(r0+q)*33+bl]=acc[q];
  }
  __syncthreads();
  // ---- tv = G Qi rhs (via M1^T) ----
  #pragma unroll
  for (int q=0;q<16;++q) acc[q]=0.f;
  #pragma unroll 2
  for (int j=0;j<128;++j){
    float rv = bufA[j*33+bl];
    const float4* mp = (const float4*)&M1[j*128+r0];
    #pragma unroll
    for (int q4=0;q4<4;++q4){
      float4 mv = mp[q4];
      acc[4*q4+0]=fmaf(mv.x,rv,acc[4*q4+0]);
      acc[4*q4+1]=fmaf(mv.y,rv,acc[4*q4+1]);
      acc[4*q4+2]=fmaf(mv.z,rv,acc[4*q4+2]);
      acc[4*q4+3]=fmaf(mv.w,rv,acc[4*q4+3]);
    }
  }
  #pragma unroll
  for (int q=0;q<16;++q) TV[(r0+q)*B_TOT+b]=acc[q];
}

// ---- k_D: final iteration tail (v, dz, z, qz) ----
__global__ __launch_bounds__(256) void k_D(const float* __restrict__ G,
    const float* __restrict__ Qi, const float* __restrict__ RHS,
    const float* __restrict__ Y, const float* __restrict__ ALPHA,
    float* __restrict__ Zst, float* __restrict__ QZ){
  __shared__ float y_l[128*33];
  __shared__ float v_l[128*33];
  const int t=threadIdx.x, g=t>>5, bl=t&31;
  const int b = blockIdx.x*TB + bl;
  #pragma unroll
  for (int q=0;q<16;++q){
    int i=g+8*q;
    y_l[i*33+bl] = Y[i*B_TOT+b];
  }
  const float alpha = ALPHA[b];
  __syncthreads();
  const int r0=g*16;
  float acc[16];
  #pragma unroll
  for (int q=0;q<16;++q) acc[q]=RHS[(r0+q)*B_TOT+b];
  #pragma unroll 2
  for (int j=0;j<128;++j){
    float yv = y_l[j*33+bl];
    const float4* gp=(const float4*)&G[j*128+r0];
    #pragma unroll
    for (int q4=0;q4<4;++q4){
      float4 gv=gp[q4];
      acc[4*q4+0]=fmaf(-gv.x,yv,acc[4*q4+0]);
      acc[4*q4+1]=fmaf(-gv.y,yv,acc[4*q4+1]);
      acc[4*q4+2]=fmaf(-gv.z,yv,acc[4*q4+2]);
      acc[4*q4+3]=fmaf(-gv.w,yv,acc[4*q4+3]);
    }
  }
  #pragma unroll
  for (int q=0;q<16;++q){
    v_l[(r0+q)*33+bl]=acc[q];
    float* qp=&QZ[(r0+q)*B_TOT+b];
    *qp = *qp + alpha*acc[q];
  }
  __syncthreads();
  #pragma unroll
  for (int q=0;q<16;++q) acc[q]=0.f;
  #pragma unroll 2
  for (int j=0;j<128;++j){
    float vv = v_l[j*33+bl];
    const float4* qp4=(const float4*)&Qi[j*128+r0];
    #pragma unroll
    for (int q4=0;q4<4;++q4){
      float4 qv=qp4[q4];
      acc[4*q4+0]=fmaf(qv.x,vv,acc[4*q4+0]);
      acc[4*q4+1]=fmaf(qv.y,vv,acc[4*q4+1]);
      acc[4*q4+2]=fmaf(qv.z,vv,acc[4*q4+2]);
      acc[4*q4+3]=fmaf(qv.w,vv,acc[4*q4+3]);
    }
  }
  #pragma unroll
  for (int q=0;q<16;++q){
    float* zp=&Zst[(r0+q)*B_TOT+b];
    *zp = *zp + alpha*acc[q];
  }
}

// out = log_softmax(Z.reshape(10, 32768), axis=1), Z stored n-major [i][B]
__global__ __launch_bounds__(1024) void k_logsoftmax(const float* __restrict__ Zst,
                                                     float* __restrict__ out){
  __shared__ float red[16];
  __shared__ float sval[2];
  const int r = blockIdx.x, t = threadIdx.x;
  float m = -1e30f;
  for (int k=t;k<32768;k+=1024){
    float v = Zst[(k&127)*B_TOT + r*256 + (k>>7)];
    m = fmaxf(m, v);
  }
  #pragma unroll
  for (int o=32;o>0;o>>=1) m = fmaxf(m, __shfl_down(m,o,64));
  if ((t&63)==0) red[t>>6] = m;
  __syncthreads();
  if (t==0){ float mm=red[0]; for (int w=1;w<16;++w) mm=fmaxf(mm,red[w]); sval[0]=mm; }
  __syncthreads();
  const float mx = sval[0];
  float s=0.f;
  for (int k=t;k<32768;k+=1024){
    float v = Zst[(k&127)*B_TOT + r*256 + (k>>7)];
    s += expf(v-mx);
  }
  #pragma unroll
  for (int o=32;o>0;o>>=1) s += __shfl_down(s,o,64);
  if ((t&63)==0) red[t>>6]=s;
  __syncthreads();
  if (t==0){ float ss=0.f; for (int w=0;w<16;++w) ss+=red[w]; sval[1]=logf(ss); }
  __syncthreads();
  const float lse = sval[1];
  for (int k=t;k<32768;k+=1024){
    float v = Zst[(k&127)*B_TOT + r*256 + (k>>7)];
    out[(size_t)r*32768+k] = v-mx-lse;
  }
}

extern "C" void kernel_launch(void* const* d_in, const int* in_sizes, int n_in,
                              void* d_out, int out_size, void* d_ws, size_t ws_size,
                              hipStream_t stream){
  // inputs: 0=x (unused), 1=Q[128x128], 2=p[2560x128], 3=G[128x128], 4=h[128], 5=m
  const float* Q = (const float*)d_in[1];
  const float* p = (const float*)d_in[2];
  const float* G = (const float*)d_in[3];
  const float* h = (const float*)d_in[4];
  float* ws  = (float*)d_ws;
  const int NE = 128*B_TOT;
  float* Zst = ws;                       // NE
  float* Qi  = Zst + NE;                 // 16384
  float* M1  = Qi + 16384;
  float* K   = M1 + 16384;
  float* Kd  = K + 16384;                // 128
  float* ALPHA = Kd + 128;               // 2560
  float* Pt  = ALPHA + 2560;             // NE
  float* S   = Pt + NE;
  float* LAM = S + NE;
  float* GZ  = LAM + NE;
  float* QZ  = GZ + NE;
  float* RHS = QZ + NE;
  float* TV  = RHS + NE;
  float* Y   = TV + NE;
  float* TRIQ= Y + NE;                   // 8448
  float* out = (float*)d_out;

  hipLaunchKernelGGL(k_prepA, dim3(1), dim3(256), 0, stream, Q, TRIQ);
  hipLaunchKernelGGL(k_prepB, dim3(8), dim3(256), 0, stream, TRIQ, G, Qi, M1);
  hipLaunchKernelGGL(k_kmat, dim3(64), dim3(256), 0, stream, G, M1, K, Kd);
  hipLaunchKernelGGL(k_init, dim3((NE+255)/256), dim3(256), 0, stream,
                     p, Pt, S, LAM, GZ, QZ, Zst);
  hipLaunchKernelGGL(k_B, dim3(NB), dim3(256), 0, stream,
                     G, M1, Pt, h, S, LAM, GZ, QZ, RHS, TV);
  for (int it=0; it<20; ++it){
    hipLaunchKernelGGL(k_C, dim3(B_TOT), dim3(128), 0, stream,
                       K, Kd, h, TV, S, LAM, GZ, Y, ALPHA);
    if (it < 19){
      hipLaunchKernelGGL(k_DB, dim3(NB), dim3(256), 0, stream,
                         G, Qi, M1, Pt, h, S, LAM, GZ, Y, ALPHA,
                         Zst, QZ, RHS, TV);
    } else {
      hipLaunchKernelGGL(k_D, dim3(NB), dim3(256), 0, stream,
                         G, Qi, RHS, Y, ALPHA, Zst, QZ);
    }
  }
  hipLaunchKernelGGL(k_logsoftmax, dim3(10), dim3(1024), 0, stream, Zst, out);
}